// Round 1
// baseline (10853.091 us; speedup 1.0000x reference)
//
#include <hip/hip_runtime.h>
#include <math.h>

#define NN 100000
#define FEAT 128
#define NHEAD 4

__device__ __forceinline__ void atomicMaxF(float* addr, float v) {
    if (v >= 0.f) atomicMax((int*)addr, __float_as_int(v));
    else atomicMin((unsigned int*)addr, __float_as_uint(v));
}

__device__ __forceinline__ float lrelu(float v) { return v > 0.f ? v : 0.2f * v; }

// ---- h = fin @ W, plus per-node attention logits al_src/al_dst ----
// 256 threads: 8 rows/block, 32 lanes per row, 4 cols/lane. W staged in LDS (64KB).
__global__ __launch_bounds__(256) void gemm_al_kernel(
    const float* __restrict__ in, const float* __restrict__ W,
    const float* __restrict__ a_src, const float* __restrict__ a_dst,
    float* __restrict__ h, float* __restrict__ al_s, float* __restrict__ al_d)
{
    __shared__ float Ws[FEAT * FEAT];          // exactly 64 KiB
    const int t = threadIdx.x;
    {
        const float4* W4 = (const float4*)W;
        float4* Ws4 = (float4*)Ws;
        for (int i = t; i < FEAT * FEAT / 4; i += 256) Ws4[i] = W4[i];
    }
    __syncthreads();
    const float4* Ws4 = (const float4*)Ws;
    const int lane_c = t & 31;                 // column group: cols [4*lane_c, 4*lane_c+4)
    const int rowb   = t >> 5;                 // 0..7
    const int c4 = lane_c * 4;
    const float as0 = a_src[c4], as1 = a_src[c4+1], as2 = a_src[c4+2], as3 = a_src[c4+3];
    const float ad0 = a_dst[c4], ad1 = a_dst[c4+1], ad2 = a_dst[c4+2], ad3 = a_dst[c4+3];

    for (int base = blockIdx.x * 8; base < NN; base += gridDim.x * 8) {
        const int r = base + rowb;             // NN % 8 == 0, always in range
        const float4* xrow4 = (const float4*)(in + (size_t)r * FEAT);
        float a0 = 0.f, a1 = 0.f, a2 = 0.f, a3 = 0.f;
        #pragma unroll 4
        for (int k4 = 0; k4 < 32; ++k4) {
            float4 xv = xrow4[k4];             // 16B broadcast within the 32-lane row group
            float4 w0 = Ws4[(4*k4+0)*32 + lane_c];
            float4 w1 = Ws4[(4*k4+1)*32 + lane_c];
            float4 w2 = Ws4[(4*k4+2)*32 + lane_c];
            float4 w3 = Ws4[(4*k4+3)*32 + lane_c];
            a0 = fmaf(xv.x, w0.x, a0); a1 = fmaf(xv.x, w0.y, a1); a2 = fmaf(xv.x, w0.z, a2); a3 = fmaf(xv.x, w0.w, a3);
            a0 = fmaf(xv.y, w1.x, a0); a1 = fmaf(xv.y, w1.y, a1); a2 = fmaf(xv.y, w1.z, a2); a3 = fmaf(xv.y, w1.w, a3);
            a0 = fmaf(xv.z, w2.x, a0); a1 = fmaf(xv.z, w2.y, a1); a2 = fmaf(xv.z, w2.z, a2); a3 = fmaf(xv.z, w2.w, a3);
            a0 = fmaf(xv.w, w3.x, a0); a1 = fmaf(xv.w, w3.y, a1); a2 = fmaf(xv.w, w3.z, a2); a3 = fmaf(xv.w, w3.w, a3);
        }
        ((float4*)(h + (size_t)r * FEAT))[lane_c] = make_float4(a0, a1, a2, a3);
        // head-wise logits: head = lane_c>>3, 8 lanes per head
        float vs = a0*as0 + a1*as1 + a2*as2 + a3*as3;
        float vd = a0*ad0 + a1*ad1 + a2*ad2 + a3*ad3;
        vs += __shfl_xor(vs, 1); vd += __shfl_xor(vd, 1);
        vs += __shfl_xor(vs, 2); vd += __shfl_xor(vd, 2);
        vs += __shfl_xor(vs, 4); vd += __shfl_xor(vd, 4);
        if ((lane_c & 7) == 0) {
            int head = lane_c >> 3;
            al_s[r * 4 + head] = vs;
            al_d[r * 4 + head] = vd;
        }
    }
}

// ---- zero accum, init segment-max/sum ----
__global__ __launch_bounds__(256) void init_kernel(float* accum, float* m, float* s)
{
    int i = blockIdx.x * 256 + threadIdx.x;
    if (i < NN * FEAT) accum[i] = 0.f;
    if (i < NN * NHEAD) { m[i] = -INFINITY; s[i] = 0.f; }
}

// ---- pass A: segment max of leaky-relu edge scores ----
__global__ __launch_bounds__(256) void edge_max_kernel(
    const int* __restrict__ ei, int E,
    const float* __restrict__ al_s, const float* __restrict__ al_d,
    float* __restrict__ m)
{
    int i = blockIdx.x * 256 + threadIdx.x;
    if (i >= E + NN) return;
    int s, d;
    if (i < E) { s = ei[i]; d = ei[E + i]; } else { s = i - E; d = s; }
    float4 vs = ((const float4*)al_s)[s];
    float4 vd = ((const float4*)al_d)[d];
    atomicMaxF(&m[d*4+0], lrelu(vs.x + vd.x));
    atomicMaxF(&m[d*4+1], lrelu(vs.y + vd.y));
    atomicMaxF(&m[d*4+2], lrelu(vs.z + vd.z));
    atomicMaxF(&m[d*4+3], lrelu(vs.w + vd.w));
}

// ---- pass B: ex = exp(e - m[dst]); store per-edge, segment-sum ----
__global__ __launch_bounds__(256) void edge_exp_kernel(
    const int* __restrict__ ei, int E,
    const float* __restrict__ al_s, const float* __restrict__ al_d,
    const float* __restrict__ m, float* __restrict__ ssum, float* __restrict__ ex)
{
    int i = blockIdx.x * 256 + threadIdx.x;
    if (i >= E + NN) return;
    int s, d;
    if (i < E) { s = ei[i]; d = ei[E + i]; } else { s = i - E; d = s; }
    float4 vs = ((const float4*)al_s)[s];
    float4 vd = ((const float4*)al_d)[d];
    float4 mm = ((const float4*)m)[d];
    float e0 = __expf(lrelu(vs.x + vd.x) - mm.x);
    float e1 = __expf(lrelu(vs.y + vd.y) - mm.y);
    float e2 = __expf(lrelu(vs.z + vd.z) - mm.z);
    float e3 = __expf(lrelu(vs.w + vd.w) - mm.w);
    ((float4*)ex)[i] = make_float4(e0, e1, e2, e3);
    atomicAdd(&ssum[d*4+0], e0);
    atomicAdd(&ssum[d*4+1], e1);
    atomicAdd(&ssum[d*4+2], e2);
    atomicAdd(&ssum[d*4+3], e3);
}

// ---- pass C: accum[dst] += alpha * h[src], 32 lanes per edge, float4 each ----
__global__ __launch_bounds__(256) void edge_aggr_kernel(
    const int* __restrict__ ei, int E,
    const float* __restrict__ h, const float* __restrict__ ssum,
    const float* __restrict__ ex, float* __restrict__ accum)
{
    long tid = (long)blockIdx.x * 256 + threadIdx.x;
    int edge = (int)(tid >> 5);
    int lane = (int)(tid & 31);
    if (edge >= E + NN) return;
    int s, d;
    if (edge < E) { s = ei[edge]; d = ei[E + edge]; } else { s = edge - E; d = s; }
    int head = lane >> 3;
    float alpha = ex[(size_t)edge * 4 + head] / (ssum[d*4 + head] + 1e-16f);
    float4 hv = ((const float4*)(h + (size_t)s * FEAT))[lane];
    float* dst = accum + (size_t)d * FEAT + lane * 4;
    atomicAdd(dst + 0, hv.x * alpha);
    atomicAdd(dst + 1, hv.y * alpha);
    atomicAdd(dst + 2, hv.z * alpha);
    atomicAdd(dst + 3, hv.w * alpha);
}

// ---- + bias, ELU (in place) ----
__global__ __launch_bounds__(256) void finalize_kernel(float* accum, const float* __restrict__ bias)
{
    int i = blockIdx.x * 256 + threadIdx.x;
    if (i >= NN * FEAT) return;
    float v = accum[i] + bias[i & 127];
    accum[i] = v > 0.f ? v : __expf(v) - 1.f;
}

// ---- final FC (128 -> 10) + log_softmax; one wave per node ----
__global__ __launch_bounds__(256) void fc_kernel(
    const float* __restrict__ h, const float* __restrict__ fcW,
    const float* __restrict__ fcb, float* __restrict__ out)
{
    __shared__ float Wl[FEAT * 10];
    __shared__ float bl[10];
    int t = threadIdx.x;
    for (int i = t; i < FEAT * 10; i += 256) Wl[i] = fcW[i];
    if (t < 10) bl[t] = fcb[t];
    __syncthreads();
    int wv = t >> 6, lane = t & 63;
    int n = blockIdx.x * 4 + wv;
    if (n >= NN) return;
    float x0 = h[(size_t)n * FEAT + lane];
    float x1 = h[(size_t)n * FEAT + 64 + lane];
    float lg[10];
    #pragma unroll
    for (int k = 0; k < 10; ++k)
        lg[k] = x0 * Wl[lane * 10 + k] + x1 * Wl[(64 + lane) * 10 + k];
    #pragma unroll
    for (int off = 32; off >= 1; off >>= 1) {
        #pragma unroll
        for (int k = 0; k < 10; ++k) lg[k] += __shfl_xor(lg[k], off);
    }
    if (lane == 0) {
        float mx = -1e30f;
        #pragma unroll
        for (int k = 0; k < 10; ++k) { lg[k] += bl[k]; mx = fmaxf(mx, lg[k]); }
        float se = 0.f;
        #pragma unroll
        for (int k = 0; k < 10; ++k) se += __expf(lg[k] - mx);
        float lse = mx + __logf(se);
        #pragma unroll
        for (int k = 0; k < 10; ++k) out[(size_t)n * 10 + k] = lg[k] - lse;
    }
}

extern "C" void kernel_launch(void* const* d_in, const int* in_sizes, int n_in,
                              void* d_out, int out_size, void* d_ws, size_t ws_size,
                              hipStream_t stream)
{
    const float* x   = (const float*)d_in[0];
    const int*   ei  = (const int*)d_in[1];
    const float* W[3]   = {(const float*)d_in[2], (const float*)d_in[6],  (const float*)d_in[10]};
    const float* asr[3] = {(const float*)d_in[3], (const float*)d_in[7],  (const float*)d_in[11]};
    const float* ads[3] = {(const float*)d_in[4], (const float*)d_in[8],  (const float*)d_in[12]};
    const float* bs[3]  = {(const float*)d_in[5], (const float*)d_in[9],  (const float*)d_in[13]};
    const float* fcW = (const float*)d_in[14];
    const float* fcb = (const float*)d_in[15];
    const int E  = in_sizes[1] / 2;
    const int EP = E + NN;

    // workspace layout (floats): P0 (h), P1 (fin/accum), al_s, al_d, m, s, ex
    float* P0  = (float*)d_ws;
    float* P1  = P0  + (size_t)NN * FEAT;
    float* als = P1  + (size_t)NN * FEAT;
    float* ald = als + (size_t)NN * NHEAD;
    float* mb  = ald + (size_t)NN * NHEAD;
    float* sb  = mb  + (size_t)NN * NHEAD;
    float* exb = sb  + (size_t)NN * NHEAD;   // EP*4 floats

    const int eb = (EP + 255) / 256;
    const long aggr_threads = (long)EP * 32;
    const int ab = (int)((aggr_threads + 255) / 256);
    const int nb = (NN * FEAT + 255) / 256;

    const float* fin = x;
    for (int l = 0; l < 3; ++l) {
        gemm_al_kernel<<<2048, 256, 0, stream>>>(fin, W[l], asr[l], ads[l], P0, als, ald);
        // gemm has fully consumed fin (==P1 for l>0) before init overwrites it (stream order)
        init_kernel<<<nb, 256, 0, stream>>>(P1, mb, sb);
        edge_max_kernel<<<eb, 256, 0, stream>>>(ei, E, als, ald, mb);
        edge_exp_kernel<<<eb, 256, 0, stream>>>(ei, E, als, ald, mb, sb, exb);
        edge_aggr_kernel<<<ab, 256, 0, stream>>>(ei, E, P0, sb, exb, P1);
        finalize_kernel<<<nb, 256, 0, stream>>>(P1, bs[l]);
        fin = P1;
    }
    fc_kernel<<<(NN + 3) / 4, 256, 0, stream>>>(P1, fcW, fcb, (float*)d_out);
}

// Round 2
// 1110.218 us; speedup vs baseline: 9.7756x; 9.7756x over previous
//
#include <hip/hip_runtime.h>
#include <math.h>

#define NN 100000
#define FEAT 128
#define NHEAD 4
#define SCAN_B 400   // 400 * 256 = 102400 >= NN

__device__ __forceinline__ float lrelu(float v) { return v > 0.f ? v : 0.2f * v; }

// ---- h = fin @ W, plus per-node attention logits al_src/al_dst ----
// 256 threads: 8 rows/block, 32 lanes per row, 4 cols/lane. W staged in LDS (64KB).
__global__ __launch_bounds__(256) void gemm_al_kernel(
    const float* __restrict__ in, const float* __restrict__ W,
    const float* __restrict__ a_src, const float* __restrict__ a_dst,
    float* __restrict__ h, float* __restrict__ al_s, float* __restrict__ al_d)
{
    __shared__ float Ws[FEAT * FEAT];          // exactly 64 KiB
    const int t = threadIdx.x;
    {
        const float4* W4 = (const float4*)W;
        float4* Ws4 = (float4*)Ws;
        for (int i = t; i < FEAT * FEAT / 4; i += 256) Ws4[i] = W4[i];
    }
    __syncthreads();
    const float4* Ws4 = (const float4*)Ws;
    const int lane_c = t & 31;                 // column group: cols [4*lane_c, 4*lane_c+4)
    const int rowb   = t >> 5;                 // 0..7
    const int c4 = lane_c * 4;
    const float as0 = a_src[c4], as1 = a_src[c4+1], as2 = a_src[c4+2], as3 = a_src[c4+3];
    const float ad0 = a_dst[c4], ad1 = a_dst[c4+1], ad2 = a_dst[c4+2], ad3 = a_dst[c4+3];

    for (int base = blockIdx.x * 8; base < NN; base += gridDim.x * 8) {
        const int r = base + rowb;             // NN % 8 == 0, always in range
        const float4* xrow4 = (const float4*)(in + (size_t)r * FEAT);
        float a0 = 0.f, a1 = 0.f, a2 = 0.f, a3 = 0.f;
        #pragma unroll 4
        for (int k4 = 0; k4 < 32; ++k4) {
            float4 xv = xrow4[k4];             // 16B broadcast within the 32-lane row group
            float4 w0 = Ws4[(4*k4+0)*32 + lane_c];
            float4 w1 = Ws4[(4*k4+1)*32 + lane_c];
            float4 w2 = Ws4[(4*k4+2)*32 + lane_c];
            float4 w3 = Ws4[(4*k4+3)*32 + lane_c];
            a0 = fmaf(xv.x, w0.x, a0); a1 = fmaf(xv.x, w0.y, a1); a2 = fmaf(xv.x, w0.z, a2); a3 = fmaf(xv.x, w0.w, a3);
            a0 = fmaf(xv.y, w1.x, a0); a1 = fmaf(xv.y, w1.y, a1); a2 = fmaf(xv.y, w1.z, a2); a3 = fmaf(xv.y, w1.w, a3);
            a0 = fmaf(xv.z, w2.x, a0); a1 = fmaf(xv.z, w2.y, a1); a2 = fmaf(xv.z, w2.z, a2); a3 = fmaf(xv.z, w2.w, a3);
            a0 = fmaf(xv.w, w3.x, a0); a1 = fmaf(xv.w, w3.y, a1); a2 = fmaf(xv.w, w3.z, a2); a3 = fmaf(xv.w, w3.w, a3);
        }
        ((float4*)(h + (size_t)r * FEAT))[lane_c] = make_float4(a0, a1, a2, a3);
        // head-wise logits: head = lane_c>>3, 8 lanes per head
        float vs = a0*as0 + a1*as1 + a2*as2 + a3*as3;
        float vd = a0*ad0 + a1*ad1 + a2*ad2 + a3*ad3;
        vs += __shfl_xor(vs, 1); vd += __shfl_xor(vd, 1);
        vs += __shfl_xor(vs, 2); vd += __shfl_xor(vd, 2);
        vs += __shfl_xor(vs, 4); vd += __shfl_xor(vd, 4);
        if ((lane_c & 7) == 0) {
            int head = lane_c >> 3;
            al_s[r * 4 + head] = vs;
            al_d[r * 4 + head] = vd;
        }
    }
}

// ======================= CSR build (once per call) =======================

__global__ __launch_bounds__(256) void count_zero_kernel(int* counts)
{
    int i = blockIdx.x * 256 + threadIdx.x;
    if (i < NN) counts[i] = 0;
}

__global__ __launch_bounds__(256) void hist_kernel(const int* __restrict__ ei, int E, int* counts)
{
    int i = blockIdx.x * 256 + threadIdx.x;
    if (i >= E + NN) return;
    int d = (i < E) ? ei[E + i] : (i - E);
    atomicAdd(&counts[d], 1);
}

__global__ __launch_bounds__(256) void scan_part_kernel(const int* __restrict__ counts, int* partial)
{
    __shared__ int sm[256];
    int t = threadIdx.x;
    int i = blockIdx.x * 256 + t;
    sm[t] = (i < NN) ? counts[i] : 0;
    __syncthreads();
    for (int off = 128; off >= 1; off >>= 1) {
        if (t < off) sm[t] += sm[t + off];
        __syncthreads();
    }
    if (t == 0) partial[blockIdx.x] = sm[0];
}

__global__ void scan_top_kernel(int* partial)
{
    if (threadIdx.x == 0 && blockIdx.x == 0) {
        int acc = 0;
        for (int i = 0; i < SCAN_B; ++i) { int v = partial[i]; partial[i] = acc; acc += v; }
    }
}

__global__ __launch_bounds__(256) void scan_final_kernel(
    const int* __restrict__ counts, const int* __restrict__ partial,
    int* row_ptr, int* cursor, int EP)
{
    __shared__ int sm[256];
    int t = threadIdx.x, b = blockIdx.x;
    int i = b * 256 + t;
    int v = (i < NN) ? counts[i] : 0;
    sm[t] = v;
    __syncthreads();
    for (int off = 1; off < 256; off <<= 1) {
        int x = (t >= off) ? sm[t - off] : 0;
        __syncthreads();
        sm[t] += x;
        __syncthreads();
    }
    if (i < NN) {
        int excl = sm[t] - v + partial[b];
        row_ptr[i] = excl;
        cursor[i]  = excl;
    }
    if (b == 0 && t == 0) row_ptr[NN] = EP;
}

__global__ __launch_bounds__(256) void scatter_kernel(
    const int* __restrict__ ei, int E, int* cursor, int* __restrict__ colidx)
{
    int i = blockIdx.x * 256 + threadIdx.x;
    if (i >= E + NN) return;
    int s, d;
    if (i < E) { s = ei[i]; d = ei[E + i]; } else { s = i - E; d = s; }
    int pos = atomicAdd(&cursor[d], 1);
    colidx[pos] = s;
}

// ======================= fused softmax + aggregation =======================
// 32 lanes per destination node; online softmax per head (head = lane>>3);
// accumulator = float4/lane (128 floats/node); fused bias + ELU; no atomics.
__global__ __launch_bounds__(256) void aggr_csr_kernel(
    const int* __restrict__ row_ptr, const int* __restrict__ colidx,
    const float* __restrict__ h, const float* __restrict__ al_s,
    const float* __restrict__ al_d, const float* __restrict__ bias,
    float* __restrict__ out)
{
    int t = threadIdx.x;
    int node = blockIdx.x * 8 + (t >> 5);
    if (node >= NN) return;
    int lane = t & 31;
    int head = lane >> 3;
    float ald_h = al_d[node * 4 + head];
    int beg = row_ptr[node], end = row_ptr[node + 1];
    float m = -INFINITY, s = 0.f;
    float ax = 0.f, ay = 0.f, az = 0.f, aw = 0.f;
    for (int p = beg; p < end; ++p) {
        int sn = colidx[p];
        float score = lrelu(al_s[sn * 4 + head] + ald_h);
        float mn = fmaxf(m, score);
        float scale = __expf(m - mn);     // first iter: exp(-inf) = 0
        float w = __expf(score - mn);
        float4 hv = ((const float4*)(h + (size_t)sn * FEAT))[lane];
        s  = s  * scale + w;
        ax = ax * scale + w * hv.x;
        ay = ay * scale + w * hv.y;
        az = az * scale + w * hv.z;
        aw = aw * scale + w * hv.w;
        m = mn;
    }
    float inv = 1.f / (s + 1e-16f);
    float4 bv = ((const float4*)bias)[lane];
    float o0 = ax * inv + bv.x;
    float o1 = ay * inv + bv.y;
    float o2 = az * inv + bv.z;
    float o3 = aw * inv + bv.w;
    o0 = o0 > 0.f ? o0 : __expf(o0) - 1.f;
    o1 = o1 > 0.f ? o1 : __expf(o1) - 1.f;
    o2 = o2 > 0.f ? o2 : __expf(o2) - 1.f;
    o3 = o3 > 0.f ? o3 : __expf(o3) - 1.f;
    ((float4*)(out + (size_t)node * FEAT))[lane] = make_float4(o0, o1, o2, o3);
}

// ---- final FC (128 -> 10) + log_softmax; one wave per node ----
__global__ __launch_bounds__(256) void fc_kernel(
    const float* __restrict__ h, const float* __restrict__ fcW,
    const float* __restrict__ fcb, float* __restrict__ out)
{
    __shared__ float Wl[FEAT * 10];
    __shared__ float bl[10];
    int t = threadIdx.x;
    for (int i = t; i < FEAT * 10; i += 256) Wl[i] = fcW[i];
    if (t < 10) bl[t] = fcb[t];
    __syncthreads();
    int wv = t >> 6, lane = t & 63;
    int n = blockIdx.x * 4 + wv;
    if (n >= NN) return;
    float x0 = h[(size_t)n * FEAT + lane];
    float x1 = h[(size_t)n * FEAT + 64 + lane];
    float lg[10];
    #pragma unroll
    for (int k = 0; k < 10; ++k)
        lg[k] = x0 * Wl[lane * 10 + k] + x1 * Wl[(64 + lane) * 10 + k];
    #pragma unroll
    for (int off = 32; off >= 1; off >>= 1) {
        #pragma unroll
        for (int k = 0; k < 10; ++k) lg[k] += __shfl_xor(lg[k], off);
    }
    if (lane == 0) {
        float mx = -1e30f;
        #pragma unroll
        for (int k = 0; k < 10; ++k) { lg[k] += bl[k]; mx = fmaxf(mx, lg[k]); }
        float se = 0.f;
        #pragma unroll
        for (int k = 0; k < 10; ++k) se += __expf(lg[k] - mx);
        float lse = mx + __logf(se);
        #pragma unroll
        for (int k = 0; k < 10; ++k) out[(size_t)n * 10 + k] = lg[k] - lse;
    }
}

extern "C" void kernel_launch(void* const* d_in, const int* in_sizes, int n_in,
                              void* d_out, int out_size, void* d_ws, size_t ws_size,
                              hipStream_t stream)
{
    const float* x   = (const float*)d_in[0];
    const int*   ei  = (const int*)d_in[1];
    const float* W[3]   = {(const float*)d_in[2], (const float*)d_in[6],  (const float*)d_in[10]};
    const float* asr[3] = {(const float*)d_in[3], (const float*)d_in[7],  (const float*)d_in[11]};
    const float* ads[3] = {(const float*)d_in[4], (const float*)d_in[8],  (const float*)d_in[12]};
    const float* bs[3]  = {(const float*)d_in[5], (const float*)d_in[9],  (const float*)d_in[13]};
    const float* fcW = (const float*)d_in[14];
    const float* fcb = (const float*)d_in[15];
    const int E  = in_sizes[1] / 2;
    const int EP = E + NN;

    // workspace layout
    float* P0  = (float*)d_ws;                       // h           [NN*FEAT]
    float* P1  = P0  + (size_t)NN * FEAT;            // fin/accum   [NN*FEAT]
    float* als = P1  + (size_t)NN * FEAT;            // [NN*4]
    float* ald = als + (size_t)NN * NHEAD;           // [NN*4]
    int* counts  = (int*)(ald + (size_t)NN * NHEAD); // [NN]
    int* row_ptr = counts + NN;                      // [NN+1]
    int* cursor  = row_ptr + NN + 1;                 // [NN]
    int* partial = cursor + NN;                      // [SCAN_B]
    int* colidx  = partial + SCAN_B;                 // [EP]

    const int eb = (EP + 255) / 256;
    const int nb256 = (NN + 255) / 256;

    // ---- CSR build (edge structure is layer-invariant) ----
    count_zero_kernel<<<nb256, 256, 0, stream>>>(counts);
    hist_kernel<<<eb, 256, 0, stream>>>(ei, E, counts);
    scan_part_kernel<<<SCAN_B, 256, 0, stream>>>(counts, partial);
    scan_top_kernel<<<1, 64, 0, stream>>>(partial);
    scan_final_kernel<<<SCAN_B, 256, 0, stream>>>(counts, partial, row_ptr, cursor, EP);
    scatter_kernel<<<eb, 256, 0, stream>>>(ei, E, cursor, colidx);

    const float* fin = x;
    for (int l = 0; l < 3; ++l) {
        gemm_al_kernel<<<2048, 256, 0, stream>>>(fin, W[l], asr[l], ads[l], P0, als, ald);
        aggr_csr_kernel<<<(NN + 7) / 8, 256, 0, stream>>>(row_ptr, colidx, P0, als, ald, bs[l], P1);
        fin = P1;
    }
    fc_kernel<<<(NN + 3) / 4, 256, 0, stream>>>(P1, fcW, fcb, (float*)d_out);
}

// Round 3
// 846.638 us; speedup vs baseline: 12.8191x; 1.3113x over previous
//
#include <hip/hip_runtime.h>
#include <math.h>

#define NN 100000
#define FEAT 128
#define NHEAD 4
#define SCAN_B 400   // 400 * 256 = 102400 >= NN

typedef unsigned int uint;
typedef unsigned short ushort;

__device__ __forceinline__ float lrelu(float v) { return v > 0.f ? v : 0.2f * v; }

__device__ __forceinline__ ushort f2bf(float f) {          // RNE bf16
    uint u = __float_as_uint(f);
    return (ushort)((u + 0x7fffu + ((u >> 16) & 1u)) >> 16);
}
__device__ __forceinline__ float bf_lo(uint u) { return __uint_as_float(u << 16); }
__device__ __forceinline__ float bf_hi(uint u) { return __uint_as_float(u & 0xffff0000u); }

// ---- h(bf16) = fin @ W, plus per-node attention logits al_src/al_dst ----
// 256 threads = 8 groups of 32 lanes; each group computes 4 rows x 128 cols.
// W staged in LDS (64 KiB); each 16B LDS W read feeds 16 FMAs (4 rows).
__global__ __launch_bounds__(256) void gemm_al_kernel(
    const float* __restrict__ in, const float* __restrict__ W,
    const float* __restrict__ a_src, const float* __restrict__ a_dst,
    ushort* __restrict__ hbf, float* __restrict__ al_s, float* __restrict__ al_d)
{
    __shared__ float Ws[FEAT * FEAT];          // 64 KiB
    const int t = threadIdx.x;
    {
        const float4* W4 = (const float4*)W;
        float4* Ws4 = (float4*)Ws;
        for (int i = t; i < FEAT * FEAT / 4; i += 256) Ws4[i] = W4[i];
    }
    __syncthreads();
    const float4* Ws4 = (const float4*)Ws;
    const int lane_c = t & 31;                 // cols [4*lane_c, 4*lane_c+4)
    const int grp    = t >> 5;                 // 0..7 -> rows grp*4..grp*4+3
    const int c4 = lane_c * 4;
    const float as0 = a_src[c4], as1 = a_src[c4+1], as2 = a_src[c4+2], as3 = a_src[c4+3];
    const float ad0 = a_dst[c4], ad1 = a_dst[c4+1], ad2 = a_dst[c4+2], ad3 = a_dst[c4+3];

    for (int base = blockIdx.x * 32; base < NN; base += gridDim.x * 32) {
        const int r0 = base + grp * 4;
        const float4* xr0 = (const float4*)(in + (size_t)r0 * FEAT);
        const float4* xr1 = (const float4*)(in + (size_t)(r0 + 1) * FEAT);
        const float4* xr2 = (const float4*)(in + (size_t)(r0 + 2) * FEAT);
        const float4* xr3 = (const float4*)(in + (size_t)(r0 + 3) * FEAT);
        float acc[4][4];
        #pragma unroll
        for (int i = 0; i < 4; ++i) { acc[i][0]=0.f; acc[i][1]=0.f; acc[i][2]=0.f; acc[i][3]=0.f; }
        #pragma unroll 2
        for (int k4 = 0; k4 < 32; ++k4) {
            float4 xa = xr0[k4], xb = xr1[k4], xc = xr2[k4], xd = xr3[k4];
            #pragma unroll
            for (int j = 0; j < 4; ++j) {
                float4 w = Ws4[(4*k4 + j) * 32 + lane_c];
                float ka = (j==0)?xa.x:(j==1)?xa.y:(j==2)?xa.z:xa.w;
                float kb = (j==0)?xb.x:(j==1)?xb.y:(j==2)?xb.z:xb.w;
                float kc = (j==0)?xc.x:(j==1)?xc.y:(j==2)?xc.z:xc.w;
                float kd = (j==0)?xd.x:(j==1)?xd.y:(j==2)?xd.z:xd.w;
                acc[0][0]=fmaf(ka,w.x,acc[0][0]); acc[0][1]=fmaf(ka,w.y,acc[0][1]); acc[0][2]=fmaf(ka,w.z,acc[0][2]); acc[0][3]=fmaf(ka,w.w,acc[0][3]);
                acc[1][0]=fmaf(kb,w.x,acc[1][0]); acc[1][1]=fmaf(kb,w.y,acc[1][1]); acc[1][2]=fmaf(kb,w.z,acc[1][2]); acc[1][3]=fmaf(kb,w.w,acc[1][3]);
                acc[2][0]=fmaf(kc,w.x,acc[2][0]); acc[2][1]=fmaf(kc,w.y,acc[2][1]); acc[2][2]=fmaf(kc,w.z,acc[2][2]); acc[2][3]=fmaf(kc,w.w,acc[2][3]);
                acc[3][0]=fmaf(kd,w.x,acc[3][0]); acc[3][1]=fmaf(kd,w.y,acc[3][1]); acc[3][2]=fmaf(kd,w.z,acc[3][2]); acc[3][3]=fmaf(kd,w.w,acc[3][3]);
            }
        }
        #pragma unroll
        for (int i = 0; i < 4; ++i) {
            const int r = r0 + i;
            ushort4 hv;
            hv.x = f2bf(acc[i][0]); hv.y = f2bf(acc[i][1]);
            hv.z = f2bf(acc[i][2]); hv.w = f2bf(acc[i][3]);
            ((ushort4*)(hbf + (size_t)r * FEAT))[lane_c] = hv;
            float vs = acc[i][0]*as0 + acc[i][1]*as1 + acc[i][2]*as2 + acc[i][3]*as3;
            float vd = acc[i][0]*ad0 + acc[i][1]*ad1 + acc[i][2]*ad2 + acc[i][3]*ad3;
            vs += __shfl_xor(vs, 1); vd += __shfl_xor(vd, 1);
            vs += __shfl_xor(vs, 2); vd += __shfl_xor(vd, 2);
            vs += __shfl_xor(vs, 4); vd += __shfl_xor(vd, 4);
            if ((lane_c & 7) == 0) {
                int head = lane_c >> 3;
                al_s[r * 4 + head] = vs;
                al_d[r * 4 + head] = vd;
            }
        }
    }
}

// ======================= CSR build (once per call) =======================

__global__ __launch_bounds__(256) void count_zero_kernel(int* counts)
{
    int i = blockIdx.x * 256 + threadIdx.x;
    if (i < NN) counts[i] = 0;
}

__global__ __launch_bounds__(256) void hist_kernel(const int* __restrict__ ei, int E, int* counts)
{
    int i = blockIdx.x * 256 + threadIdx.x;
    if (i >= E + NN) return;
    int d = (i < E) ? ei[E + i] : (i - E);
    atomicAdd(&counts[d], 1);
}

__global__ __launch_bounds__(256) void scan_part_kernel(const int* __restrict__ counts, int* partial)
{
    __shared__ int sm[256];
    int t = threadIdx.x;
    int i = blockIdx.x * 256 + t;
    sm[t] = (i < NN) ? counts[i] : 0;
    __syncthreads();
    for (int off = 128; off >= 1; off >>= 1) {
        if (t < off) sm[t] += sm[t + off];
        __syncthreads();
    }
    if (t == 0) partial[blockIdx.x] = sm[0];
}

__global__ void scan_top_kernel(int* partial)
{
    if (threadIdx.x == 0 && blockIdx.x == 0) {
        int acc = 0;
        for (int i = 0; i < SCAN_B; ++i) { int v = partial[i]; partial[i] = acc; acc += v; }
    }
}

__global__ __launch_bounds__(256) void scan_final_kernel(
    const int* __restrict__ counts, const int* __restrict__ partial,
    int* row_ptr, int* cursor, int EP)
{
    __shared__ int sm[256];
    int t = threadIdx.x, b = blockIdx.x;
    int i = b * 256 + t;
    int v = (i < NN) ? counts[i] : 0;
    sm[t] = v;
    __syncthreads();
    for (int off = 1; off < 256; off <<= 1) {
        int x = (t >= off) ? sm[t - off] : 0;
        __syncthreads();
        sm[t] += x;
        __syncthreads();
    }
    if (i < NN) {
        int excl = sm[t] - v + partial[b];
        row_ptr[i] = excl;
        cursor[i]  = excl;
    }
    if (b == 0 && t == 0) row_ptr[NN] = EP;
}

__global__ __launch_bounds__(256) void scatter_kernel(
    const int* __restrict__ ei, int E, int* cursor, int* __restrict__ colidx)
{
    int i = blockIdx.x * 256 + threadIdx.x;
    if (i >= E + NN) return;
    int s, d;
    if (i < E) { s = ei[i]; d = ei[E + i]; } else { s = i - E; d = s; }
    int pos = atomicAdd(&cursor[d], 1);
    colidx[pos] = s;
}

// ======================= fused softmax + aggregation =======================
// 16 lanes per destination node (4 nodes/wave); head = lane>>2.
// Plain exp (softmax is shift-invariant; scores are O(+-6) -> safe in fp32).
// Edge loop unrolled x4 with batched loads -> 4 gathers in flight per node.
__global__ __launch_bounds__(256) void aggr_csr_kernel(
    const int* __restrict__ row_ptr, const int* __restrict__ colidx,
    const ushort* __restrict__ hbf, const float* __restrict__ al_s,
    const float* __restrict__ al_d, const float* __restrict__ bias,
    float* __restrict__ out)
{
    int t = threadIdx.x;
    int node = blockIdx.x * 16 + (t >> 4);
    if (node >= NN) return;
    int lane = t & 15;
    int head = lane >> 2;
    float ald_h = al_d[node * 4 + head];
    int beg = row_ptr[node], end = row_ptr[node + 1];

    float ssum = 0.f;
    float a0=0.f,a1=0.f,a2=0.f,a3=0.f,a4=0.f,a5=0.f,a6=0.f,a7=0.f;

    int p = beg;
    for (; p + 4 <= end; p += 4) {
        int s0 = colidx[p], s1 = colidx[p+1], s2 = colidx[p+2], s3 = colidx[p+3];
        float w0 = __expf(lrelu(al_s[s0*4 + head] + ald_h));
        float w1 = __expf(lrelu(al_s[s1*4 + head] + ald_h));
        float w2 = __expf(lrelu(al_s[s2*4 + head] + ald_h));
        float w3 = __expf(lrelu(al_s[s3*4 + head] + ald_h));
        uint4 h0 = ((const uint4*)(hbf + (size_t)s0 * FEAT))[lane];
        uint4 h1 = ((const uint4*)(hbf + (size_t)s1 * FEAT))[lane];
        uint4 h2 = ((const uint4*)(hbf + (size_t)s2 * FEAT))[lane];
        uint4 h3 = ((const uint4*)(hbf + (size_t)s3 * FEAT))[lane];
        ssum += (w0 + w1) + (w2 + w3);
        a0 = fmaf(w0, bf_lo(h0.x), a0); a1 = fmaf(w0, bf_hi(h0.x), a1);
        a2 = fmaf(w0, bf_lo(h0.y), a2); a3 = fmaf(w0, bf_hi(h0.y), a3);
        a4 = fmaf(w0, bf_lo(h0.z), a4); a5 = fmaf(w0, bf_hi(h0.z), a5);
        a6 = fmaf(w0, bf_lo(h0.w), a6); a7 = fmaf(w0, bf_hi(h0.w), a7);
        a0 = fmaf(w1, bf_lo(h1.x), a0); a1 = fmaf(w1, bf_hi(h1.x), a1);
        a2 = fmaf(w1, bf_lo(h1.y), a2); a3 = fmaf(w1, bf_hi(h1.y), a3);
        a4 = fmaf(w1, bf_lo(h1.z), a4); a5 = fmaf(w1, bf_hi(h1.z), a5);
        a6 = fmaf(w1, bf_lo(h1.w), a6); a7 = fmaf(w1, bf_hi(h1.w), a7);
        a0 = fmaf(w2, bf_lo(h2.x), a0); a1 = fmaf(w2, bf_hi(h2.x), a1);
        a2 = fmaf(w2, bf_lo(h2.y), a2); a3 = fmaf(w2, bf_hi(h2.y), a3);
        a4 = fmaf(w2, bf_lo(h2.z), a4); a5 = fmaf(w2, bf_hi(h2.z), a5);
        a6 = fmaf(w2, bf_lo(h2.w), a6); a7 = fmaf(w2, bf_hi(h2.w), a7);
        a0 = fmaf(w3, bf_lo(h3.x), a0); a1 = fmaf(w3, bf_hi(h3.x), a1);
        a2 = fmaf(w3, bf_lo(h3.y), a2); a3 = fmaf(w3, bf_hi(h3.y), a3);
        a4 = fmaf(w3, bf_lo(h3.z), a4); a5 = fmaf(w3, bf_hi(h3.z), a5);
        a6 = fmaf(w3, bf_lo(h3.w), a6); a7 = fmaf(w3, bf_hi(h3.w), a7);
    }
    for (; p < end; ++p) {
        int sn = colidx[p];
        float w = __expf(lrelu(al_s[sn*4 + head] + ald_h));
        uint4 hv = ((const uint4*)(hbf + (size_t)sn * FEAT))[lane];
        ssum += w;
        a0 = fmaf(w, bf_lo(hv.x), a0); a1 = fmaf(w, bf_hi(hv.x), a1);
        a2 = fmaf(w, bf_lo(hv.y), a2); a3 = fmaf(w, bf_hi(hv.y), a3);
        a4 = fmaf(w, bf_lo(hv.z), a4); a5 = fmaf(w, bf_hi(hv.z), a5);
        a6 = fmaf(w, bf_lo(hv.w), a6); a7 = fmaf(w, bf_hi(hv.w), a7);
    }
    float inv = 1.f / (ssum + 1e-16f);
    const float* bp = bias + lane * 8;
    float o[8] = {a0,a1,a2,a3,a4,a5,a6,a7};
    float4 ov0, ov1;
    #pragma unroll
    for (int k = 0; k < 8; ++k) {
        float v = o[k] * inv + bp[k];
        o[k] = v > 0.f ? v : __expf(v) - 1.f;
    }
    ov0 = make_float4(o[0], o[1], o[2], o[3]);
    ov1 = make_float4(o[4], o[5], o[6], o[7]);
    float4* orow = (float4*)(out + (size_t)node * FEAT + lane * 8);
    orow[0] = ov0;
    orow[1] = ov1;
}

// ---- final FC (128 -> 10) + log_softmax; one wave per node ----
__global__ __launch_bounds__(256) void fc_kernel(
    const float* __restrict__ h, const float* __restrict__ fcW,
    const float* __restrict__ fcb, float* __restrict__ out)
{
    __shared__ float Wl[FEAT * 10];
    __shared__ float bl[10];
    int t = threadIdx.x;
    for (int i = t; i < FEAT * 10; i += 256) Wl[i] = fcW[i];
    if (t < 10) bl[t] = fcb[t];
    __syncthreads();
    int wv = t >> 6, lane = t & 63;
    int n = blockIdx.x * 4 + wv;
    if (n >= NN) return;
    float x0 = h[(size_t)n * FEAT + lane];
    float x1 = h[(size_t)n * FEAT + 64 + lane];
    float lg[10];
    #pragma unroll
    for (int k = 0; k < 10; ++k)
        lg[k] = x0 * Wl[lane * 10 + k] + x1 * Wl[(64 + lane) * 10 + k];
    #pragma unroll
    for (int off = 32; off >= 1; off >>= 1) {
        #pragma unroll
        for (int k = 0; k < 10; ++k) lg[k] += __shfl_xor(lg[k], off);
    }
    if (lane == 0) {
        float mx = -1e30f;
        #pragma unroll
        for (int k = 0; k < 10; ++k) { lg[k] += bl[k]; mx = fmaxf(mx, lg[k]); }
        float se = 0.f;
        #pragma unroll
        for (int k = 0; k < 10; ++k) se += __expf(lg[k] - mx);
        float lse = mx + __logf(se);
        #pragma unroll
        for (int k = 0; k < 10; ++k) out[(size_t)n * 10 + k] = lg[k] - lse;
    }
}

extern "C" void kernel_launch(void* const* d_in, const int* in_sizes, int n_in,
                              void* d_out, int out_size, void* d_ws, size_t ws_size,
                              hipStream_t stream)
{
    const float* x   = (const float*)d_in[0];
    const int*   ei  = (const int*)d_in[1];
    const float* W[3]   = {(const float*)d_in[2], (const float*)d_in[6],  (const float*)d_in[10]};
    const float* asr[3] = {(const float*)d_in[3], (const float*)d_in[7],  (const float*)d_in[11]};
    const float* ads[3] = {(const float*)d_in[4], (const float*)d_in[8],  (const float*)d_in[12]};
    const float* bs[3]  = {(const float*)d_in[5], (const float*)d_in[9],  (const float*)d_in[13]};
    const float* fcW = (const float*)d_in[14];
    const float* fcb = (const float*)d_in[15];
    const int E  = in_sizes[1] / 2;
    const int EP = E + NN;

    // workspace layout
    ushort* hbf = (ushort*)d_ws;                     // h bf16 [NN*FEAT]
    float* P1   = (float*)(hbf + (size_t)NN * FEAT); // fin/accum [NN*FEAT] fp32
    float* als  = P1  + (size_t)NN * FEAT;           // [NN*4]
    float* ald  = als + (size_t)NN * NHEAD;          // [NN*4]
    int* counts  = (int*)(ald + (size_t)NN * NHEAD); // [NN]
    int* row_ptr = counts + NN;                      // [NN+1]
    int* cursor  = row_ptr + NN + 1;                 // [NN]
    int* partial = cursor + NN;                      // [SCAN_B]
    int* colidx  = partial + SCAN_B;                 // [EP]

    const int eb = (EP + 255) / 256;
    const int nb256 = (NN + 255) / 256;

    // ---- CSR build (edge structure is layer-invariant) ----
    count_zero_kernel<<<nb256, 256, 0, stream>>>(counts);
    hist_kernel<<<eb, 256, 0, stream>>>(ei, E, counts);
    scan_part_kernel<<<SCAN_B, 256, 0, stream>>>(counts, partial);
    scan_top_kernel<<<1, 64, 0, stream>>>(partial);
    scan_final_kernel<<<SCAN_B, 256, 0, stream>>>(counts, partial, row_ptr, cursor, EP);
    scatter_kernel<<<eb, 256, 0, stream>>>(ei, E, cursor, colidx);

    const float* fin = x;
    for (int l = 0; l < 3; ++l) {
        gemm_al_kernel<<<1563, 256, 0, stream>>>(fin, W[l], asr[l], ads[l], hbf, als, ald);
        aggr_csr_kernel<<<(NN + 15) / 16, 256, 0, stream>>>(row_ptr, colidx, hbf, als, ald, bs[l], P1);
        fin = P1;
    }
    fc_kernel<<<(NN + 3) / 4, 256, 0, stream>>>(P1, fcW, fcb, (float*)d_out);
}

// Round 4
// 722.678 us; speedup vs baseline: 15.0179x; 1.1715x over previous
//
#include <hip/hip_runtime.h>
#include <math.h>

#define NN 100000
#define FEAT 128
#define NHEAD 4
#define BSH 9                      // 512 nodes per bucket
#define BNODES 512
#define NBUCK 196                  // ceil(NN / 512)
#define BCAP 16384                 // colidx LDS image capacity (avg span ~8700)
#define PA_EPT 16                  // phase-A edges per thread

typedef unsigned int uint;
typedef unsigned short ushort;

__device__ __forceinline__ float lrelu(float v) { return v > 0.f ? v : 0.2f * v; }

__device__ __forceinline__ ushort f2bf(float f) {          // RNE bf16
    uint u = __float_as_uint(f);
    return (ushort)((u + 0x7fffu + ((u >> 16) & 1u)) >> 16);
}
__device__ __forceinline__ float bf_lo(uint u) { return __uint_as_float(u << 16); }
__device__ __forceinline__ float bf_hi(uint u) { return __uint_as_float(u & 0xffff0000u); }

// ---- h(bf16) = fin @ W, plus per-node attention logits al_src/al_dst ----
__global__ __launch_bounds__(256) void gemm_al_kernel(
    const float* __restrict__ in, const float* __restrict__ W,
    const float* __restrict__ a_src, const float* __restrict__ a_dst,
    ushort* __restrict__ hbf, float* __restrict__ al_s, float* __restrict__ al_d)
{
    __shared__ float Ws[FEAT * FEAT];          // 64 KiB
    const int t = threadIdx.x;
    {
        const float4* W4 = (const float4*)W;
        float4* Ws4 = (float4*)Ws;
        for (int i = t; i < FEAT * FEAT / 4; i += 256) Ws4[i] = W4[i];
    }
    __syncthreads();
    const float4* Ws4 = (const float4*)Ws;
    const int lane_c = t & 31;
    const int grp    = t >> 5;
    const int c4 = lane_c * 4;
    const float as0 = a_src[c4], as1 = a_src[c4+1], as2 = a_src[c4+2], as3 = a_src[c4+3];
    const float ad0 = a_dst[c4], ad1 = a_dst[c4+1], ad2 = a_dst[c4+2], ad3 = a_dst[c4+3];

    for (int base = blockIdx.x * 32; base < NN; base += gridDim.x * 32) {
        const int r0 = base + grp * 4;
        const float4* xr0 = (const float4*)(in + (size_t)r0 * FEAT);
        const float4* xr1 = (const float4*)(in + (size_t)(r0 + 1) * FEAT);
        const float4* xr2 = (const float4*)(in + (size_t)(r0 + 2) * FEAT);
        const float4* xr3 = (const float4*)(in + (size_t)(r0 + 3) * FEAT);
        float acc[4][4];
        #pragma unroll
        for (int i = 0; i < 4; ++i) { acc[i][0]=0.f; acc[i][1]=0.f; acc[i][2]=0.f; acc[i][3]=0.f; }
        #pragma unroll 2
        for (int k4 = 0; k4 < 32; ++k4) {
            float4 xa = xr0[k4], xb = xr1[k4], xc = xr2[k4], xd = xr3[k4];
            #pragma unroll
            for (int j = 0; j < 4; ++j) {
                float4 w = Ws4[(4*k4 + j) * 32 + lane_c];
                float ka = (j==0)?xa.x:(j==1)?xa.y:(j==2)?xa.z:xa.w;
                float kb = (j==0)?xb.x:(j==1)?xb.y:(j==2)?xb.z:xb.w;
                float kc = (j==0)?xc.x:(j==1)?xc.y:(j==2)?xc.z:xc.w;
                float kd = (j==0)?xd.x:(j==1)?xd.y:(j==2)?xd.z:xd.w;
                acc[0][0]=fmaf(ka,w.x,acc[0][0]); acc[0][1]=fmaf(ka,w.y,acc[0][1]); acc[0][2]=fmaf(ka,w.z,acc[0][2]); acc[0][3]=fmaf(ka,w.w,acc[0][3]);
                acc[1][0]=fmaf(kb,w.x,acc[1][0]); acc[1][1]=fmaf(kb,w.y,acc[1][1]); acc[1][2]=fmaf(kb,w.z,acc[1][2]); acc[1][3]=fmaf(kb,w.w,acc[1][3]);
                acc[2][0]=fmaf(kc,w.x,acc[2][0]); acc[2][1]=fmaf(kc,w.y,acc[2][1]); acc[2][2]=fmaf(kc,w.z,acc[2][2]); acc[2][3]=fmaf(kc,w.w,acc[2][3]);
                acc[3][0]=fmaf(kd,w.x,acc[3][0]); acc[3][1]=fmaf(kd,w.y,acc[3][1]); acc[3][2]=fmaf(kd,w.z,acc[3][2]); acc[3][3]=fmaf(kd,w.w,acc[3][3]);
            }
        }
        #pragma unroll
        for (int i = 0; i < 4; ++i) {
            const int r = r0 + i;
            ushort4 hv;
            hv.x = f2bf(acc[i][0]); hv.y = f2bf(acc[i][1]);
            hv.z = f2bf(acc[i][2]); hv.w = f2bf(acc[i][3]);
            ((ushort4*)(hbf + (size_t)r * FEAT))[lane_c] = hv;
            float vs = acc[i][0]*as0 + acc[i][1]*as1 + acc[i][2]*as2 + acc[i][3]*as3;
            float vd = acc[i][0]*ad0 + acc[i][1]*ad1 + acc[i][2]*ad2 + acc[i][3]*ad3;
            vs += __shfl_xor(vs, 1); vd += __shfl_xor(vd, 1);
            vs += __shfl_xor(vs, 2); vd += __shfl_xor(vd, 2);
            vs += __shfl_xor(vs, 4); vd += __shfl_xor(vd, 4);
            if ((lane_c & 7) == 0) {
                int head = lane_c >> 3;
                al_s[r * 4 + head] = vs;
                al_d[r * 4 + head] = vd;
            }
        }
    }
}

// ======================= CSR build: bucketed counting sort =======================

__global__ void zero_small_kernel(int* bsize)
{
    int t = threadIdx.x;
    if (t < NBUCK) bsize[t] = 0;
}

__global__ __launch_bounds__(256) void bucket_hist_kernel(
    const int* __restrict__ ei, int E, int* bsize)
{
    __shared__ int lh[NBUCK];
    int t = threadIdx.x;
    if (t < NBUCK) lh[t] = 0;
    __syncthreads();
    int stride = gridDim.x * 256;
    for (int i = blockIdx.x * 256 + t; i < E + NN; i += stride) {
        int d = (i < E) ? ei[E + i] : (i - E);
        atomicAdd(&lh[d >> BSH], 1);
    }
    __syncthreads();
    if (t < NBUCK && lh[t]) atomicAdd(&bsize[t], lh[t]);
}

__global__ void bucket_scan_kernel(const int* __restrict__ bsize, int* bbase, int* bcursor)
{
    if (threadIdx.x == 0) {
        int acc = 0;
        for (int b = 0; b < NBUCK; ++b) { bbase[b] = acc; bcursor[b] = acc; acc += bsize[b]; }
        bbase[NBUCK] = acc;
    }
}

// Each block: 4096 edges in registers; local hist -> one global reservation per
// bucket -> bucket-contiguous (dst,src) pair writes (runs of ~170B).
__global__ __launch_bounds__(256) void phaseA_bin_kernel(
    const int* __restrict__ ei, int E, int* bcursor, int2* __restrict__ pairs)
{
    __shared__ int lh[NBUCK], lb[NBUCK];
    int t = threadIdx.x;
    if (t < NBUCK) lh[t] = 0;
    __syncthreads();
    int base = blockIdx.x * (256 * PA_EPT) + t;
    int s[PA_EPT], d[PA_EPT];
    #pragma unroll
    for (int k = 0; k < PA_EPT; ++k) {
        int i = base + k * 256;
        if (i < E)            { s[k] = ei[i]; d[k] = ei[E + i]; }
        else if (i < E + NN)  { s[k] = i - E; d[k] = s[k]; }
        else                  { s[k] = 0; d[k] = -1; }
        if (d[k] >= 0) atomicAdd(&lh[d[k] >> BSH], 1);
    }
    __syncthreads();
    if (t < NBUCK) {
        int c = lh[t];
        lb[t] = c ? atomicAdd(&bcursor[t], c) : 0;
        lh[t] = 0;
    }
    __syncthreads();
    #pragma unroll
    for (int k = 0; k < PA_EPT; ++k) {
        if (d[k] >= 0) {
            int b = d[k] >> BSH;
            int off = atomicAdd(&lh[b], 1);
            pairs[lb[b] + off] = make_int2(d[k], s[k]);
        }
    }
}

// One block per bucket: per-node hist + scan -> row_ptr (coalesced); build
// colidx image in LDS via LDS atomics; copy out coalesced.
__global__ __launch_bounds__(256) void phaseB_kernel(
    const int2* __restrict__ pairs, const int* __restrict__ bbase,
    int* __restrict__ row_ptr, int* __restrict__ colidx, int EP)
{
    __shared__ int nh[BNODES];
    __shared__ int ex[BNODES];
    __shared__ int ss[256];
    __shared__ int img[BCAP];
    int b = blockIdx.x, t = threadIdx.x;
    int node0 = b << BSH;
    int nend = min(NN - node0, BNODES);
    int pb = bbase[b], pe = bbase[b + 1];
    int span = pe - pb;
    for (int j = t; j < BNODES; j += 256) nh[j] = 0;
    __syncthreads();
    for (int i = t; i < span; i += 256)
        atomicAdd(&nh[pairs[pb + i].x - node0], 1);
    __syncthreads();
    // exclusive scan of nh[0..512) -> ex; 2 entries/thread + 256-wide Hillis-Steele
    int v0 = nh[2 * t], v1 = nh[2 * t + 1];
    int ps = v0 + v1;
    ss[t] = ps;
    __syncthreads();
    #pragma unroll
    for (int off = 1; off < 256; off <<= 1) {
        int x = (t >= off) ? ss[t - off] : 0;
        __syncthreads();
        ss[t] += x;
        __syncthreads();
    }
    int ep = ss[t] - ps;
    ex[2 * t] = ep;
    ex[2 * t + 1] = ep + v0;
    __syncthreads();
    for (int j = t; j < nend; j += 256) row_ptr[node0 + j] = pb + ex[j];
    if (b == NBUCK - 1 && t == 0) row_ptr[NN] = EP;
    for (int j = t; j < BNODES; j += 256) nh[j] = ex[j];   // reuse as cursors
    __syncthreads();
    if (span <= BCAP) {
        for (int i = t; i < span; i += 256) {
            int2 p = pairs[pb + i];
            int pos = atomicAdd(&nh[p.x - node0], 1);
            img[pos] = p.y;
        }
        __syncthreads();
        for (int i = t; i < span; i += 256) colidx[pb + i] = img[i];
    } else {  // overflow fallback (never hit for this graph)
        for (int i = t; i < span; i += 256) {
            int2 p = pairs[pb + i];
            int pos = atomicAdd(&nh[p.x - node0], 1);
            colidx[pb + pos] = p.y;
        }
    }
}

// ======================= fused softmax + aggregation =======================
__global__ __launch_bounds__(256) void aggr_csr_kernel(
    const int* __restrict__ row_ptr, const int* __restrict__ colidx,
    const ushort* __restrict__ hbf, const float* __restrict__ al_s,
    const float* __restrict__ al_d, const float* __restrict__ bias,
    float* __restrict__ out)
{
    int t = threadIdx.x;
    int node = blockIdx.x * 16 + (t >> 4);
    if (node >= NN) return;
    int lane = t & 15;
    int head = lane >> 2;
    float ald_h = al_d[node * 4 + head];
    int beg = row_ptr[node], end = row_ptr[node + 1];

    float ssum = 0.f;
    float a0=0.f,a1=0.f,a2=0.f,a3=0.f,a4=0.f,a5=0.f,a6=0.f,a7=0.f;

    int p = beg;
    for (; p + 4 <= end; p += 4) {
        int s0 = colidx[p], s1 = colidx[p+1], s2 = colidx[p+2], s3 = colidx[p+3];
        float w0 = __expf(lrelu(al_s[s0*4 + head] + ald_h));
        float w1 = __expf(lrelu(al_s[s1*4 + head] + ald_h));
        float w2 = __expf(lrelu(al_s[s2*4 + head] + ald_h));
        float w3 = __expf(lrelu(al_s[s3*4 + head] + ald_h));
        uint4 h0 = ((const uint4*)(hbf + (size_t)s0 * FEAT))[lane];
        uint4 h1 = ((const uint4*)(hbf + (size_t)s1 * FEAT))[lane];
        uint4 h2 = ((const uint4*)(hbf + (size_t)s2 * FEAT))[lane];
        uint4 h3 = ((const uint4*)(hbf + (size_t)s3 * FEAT))[lane];
        ssum += (w0 + w1) + (w2 + w3);
        a0 = fmaf(w0, bf_lo(h0.x), a0); a1 = fmaf(w0, bf_hi(h0.x), a1);
        a2 = fmaf(w0, bf_lo(h0.y), a2); a3 = fmaf(w0, bf_hi(h0.y), a3);
        a4 = fmaf(w0, bf_lo(h0.z), a4); a5 = fmaf(w0, bf_hi(h0.z), a5);
        a6 = fmaf(w0, bf_lo(h0.w), a6); a7 = fmaf(w0, bf_hi(h0.w), a7);
        a0 = fmaf(w1, bf_lo(h1.x), a0); a1 = fmaf(w1, bf_hi(h1.x), a1);
        a2 = fmaf(w1, bf_lo(h1.y), a2); a3 = fmaf(w1, bf_hi(h1.y), a3);
        a4 = fmaf(w1, bf_lo(h1.z), a4); a5 = fmaf(w1, bf_hi(h1.z), a5);
        a6 = fmaf(w1, bf_lo(h1.w), a6); a7 = fmaf(w1, bf_hi(h1.w), a7);
        a0 = fmaf(w2, bf_lo(h2.x), a0); a1 = fmaf(w2, bf_hi(h2.x), a1);
        a2 = fmaf(w2, bf_lo(h2.y), a2); a3 = fmaf(w2, bf_hi(h2.y), a3);
        a4 = fmaf(w2, bf_lo(h2.z), a4); a5 = fmaf(w2, bf_hi(h2.z), a5);
        a6 = fmaf(w2, bf_lo(h2.w), a6); a7 = fmaf(w2, bf_hi(h2.w), a7);
        a0 = fmaf(w3, bf_lo(h3.x), a0); a1 = fmaf(w3, bf_hi(h3.x), a1);
        a2 = fmaf(w3, bf_lo(h3.y), a2); a3 = fmaf(w3, bf_hi(h3.y), a3);
        a4 = fmaf(w3, bf_lo(h3.z), a4); a5 = fmaf(w3, bf_hi(h3.z), a5);
        a6 = fmaf(w3, bf_lo(h3.w), a6); a7 = fmaf(w3, bf_hi(h3.w), a7);
    }
    for (; p < end; ++p) {
        int sn = colidx[p];
        float w = __expf(lrelu(al_s[sn*4 + head] + ald_h));
        uint4 hv = ((const uint4*)(hbf + (size_t)sn * FEAT))[lane];
        ssum += w;
        a0 = fmaf(w, bf_lo(hv.x), a0); a1 = fmaf(w, bf_hi(hv.x), a1);
        a2 = fmaf(w, bf_lo(hv.y), a2); a3 = fmaf(w, bf_hi(hv.y), a3);
        a4 = fmaf(w, bf_lo(hv.z), a4); a5 = fmaf(w, bf_hi(hv.z), a5);
        a6 = fmaf(w, bf_lo(hv.w), a6); a7 = fmaf(w, bf_hi(hv.w), a7);
    }
    float inv = 1.f / (ssum + 1e-16f);
    const float* bp = bias + lane * 8;
    float o[8] = {a0,a1,a2,a3,a4,a5,a6,a7};
    #pragma unroll
    for (int k = 0; k < 8; ++k) {
        float v = o[k] * inv + bp[k];
        o[k] = v > 0.f ? v : __expf(v) - 1.f;
    }
    float4* orow = (float4*)(out + (size_t)node * FEAT + lane * 8);
    orow[0] = make_float4(o[0], o[1], o[2], o[3]);
    orow[1] = make_float4(o[4], o[5], o[6], o[7]);
}

// ---- final FC (128 -> 10) + log_softmax; one wave per node ----
__global__ __launch_bounds__(256) void fc_kernel(
    const float* __restrict__ h, const float* __restrict__ fcW,
    const float* __restrict__ fcb, float* __restrict__ out)
{
    __shared__ float Wl[FEAT * 10];
    __shared__ float bl[10];
    int t = threadIdx.x;
    for (int i = t; i < FEAT * 10; i += 256) Wl[i] = fcW[i];
    if (t < 10) bl[t] = fcb[t];
    __syncthreads();
    int wv = t >> 6, lane = t & 63;
    int n = blockIdx.x * 4 + wv;
    if (n >= NN) return;
    float x0 = h[(size_t)n * FEAT + lane];
    float x1 = h[(size_t)n * FEAT + 64 + lane];
    float lg[10];
    #pragma unroll
    for (int k = 0; k < 10; ++k)
        lg[k] = x0 * Wl[lane * 10 + k] + x1 * Wl[(64 + lane) * 10 + k];
    #pragma unroll
    for (int off = 32; off >= 1; off >>= 1) {
        #pragma unroll
        for (int k = 0; k < 10; ++k) lg[k] += __shfl_xor(lg[k], off);
    }
    if (lane == 0) {
        float mx = -1e30f;
        #pragma unroll
        for (int k = 0; k < 10; ++k) { lg[k] += bl[k]; mx = fmaxf(mx, lg[k]); }
        float se = 0.f;
        #pragma unroll
        for (int k = 0; k < 10; ++k) se += __expf(lg[k] - mx);
        float lse = mx + __logf(se);
        #pragma unroll
        for (int k = 0; k < 10; ++k) out[(size_t)n * 10 + k] = lg[k] - lse;
    }
}

extern "C" void kernel_launch(void* const* d_in, const int* in_sizes, int n_in,
                              void* d_out, int out_size, void* d_ws, size_t ws_size,
                              hipStream_t stream)
{
    const float* x   = (const float*)d_in[0];
    const int*   ei  = (const int*)d_in[1];
    const float* W[3]   = {(const float*)d_in[2], (const float*)d_in[6],  (const float*)d_in[10]};
    const float* asr[3] = {(const float*)d_in[3], (const float*)d_in[7],  (const float*)d_in[11]};
    const float* ads[3] = {(const float*)d_in[4], (const float*)d_in[8],  (const float*)d_in[12]};
    const float* bs[3]  = {(const float*)d_in[5], (const float*)d_in[9],  (const float*)d_in[13]};
    const float* fcW = (const float*)d_in[14];
    const float* fcb = (const float*)d_in[15];
    const int E  = in_sizes[1] / 2;
    const int EP = E + NN;

    // workspace layout
    ushort* hbf  = (ushort*)d_ws;                      // [NN*FEAT] bf16
    float* P1    = (float*)(hbf + (size_t)NN * FEAT);  // [NN*FEAT] fp32
    float* als   = P1  + (size_t)NN * FEAT;            // [NN*4]
    float* ald   = als + (size_t)NN * NHEAD;           // [NN*4]
    int* row_ptr = (int*)(ald + (size_t)NN * NHEAD);   // [NN+1]
    int* bsize   = row_ptr + NN + 1;                   // [NBUCK]
    int* bbase   = bsize + NBUCK;                      // [NBUCK+1]
    int* bcursor = bbase + NBUCK + 1;                  // [NBUCK]
    int2* pairs  = (int2*)(bcursor + NBUCK);           // [EP]
    int* colidx  = (int*)(pairs + (size_t)EP);         // [EP]

    // ---- CSR build (once; graph is layer-invariant) ----
    zero_small_kernel<<<1, 256, 0, stream>>>(bsize);
    bucket_hist_kernel<<<1024, 256, 0, stream>>>(ei, E, bsize);
    bucket_scan_kernel<<<1, 64, 0, stream>>>(bsize, bbase, bcursor);
    phaseA_bin_kernel<<<(EP + 256*PA_EPT - 1) / (256*PA_EPT), 256, 0, stream>>>(ei, E, bcursor, pairs);
    phaseB_kernel<<<NBUCK, 256, 0, stream>>>(pairs, bbase, row_ptr, colidx, EP);

    const float* fin = x;
    for (int l = 0; l < 3; ++l) {
        gemm_al_kernel<<<1563, 256, 0, stream>>>(fin, W[l], asr[l], ads[l], hbf, als, ald);
        aggr_csr_kernel<<<(NN + 15) / 16, 256, 0, stream>>>(row_ptr, colidx, hbf, als, ald, bs[l], P1);
        fin = P1;
    }
    fc_kernel<<<(NN + 3) / 4, 256, 0, stream>>>(P1, fcW, fcb, (float*)d_out);
}

// Round 5
// 562.813 us; speedup vs baseline: 19.2836x; 1.2840x over previous
//
#include <hip/hip_runtime.h>
#include <math.h>

#define NN 100000
#define FEAT 128
#define NHEAD 4
#define BSH 9                      // 512 nodes per bucket
#define BNODES 512
#define NBUCK 196                  // ceil(NN / 512)
#define BCAP 16384                 // colidx LDS image capacity (avg span ~8700)
#define PA_EPT 16                  // phase-A edges per thread
#define GTILES 6250                // 100000 / 16

typedef unsigned int uint;
typedef unsigned short ushort;
typedef __attribute__((ext_vector_type(8))) short short8;
typedef __attribute__((ext_vector_type(4))) float fx4;

__device__ __forceinline__ float lrelu(float v) { return v > 0.f ? v : 0.2f * v; }

__device__ __forceinline__ ushort f2bf(float f) {          // RNE bf16
    uint u = __float_as_uint(f);
    return (ushort)((u + 0x7fffu + ((u >> 16) & 1u)) >> 16);
}
__device__ __forceinline__ float bf_lo(uint u) { return __uint_as_float(u << 16); }
__device__ __forceinline__ float bf_hi(uint u) { return __uint_as_float(u & 0xffff0000u); }
__device__ __forceinline__ float bfu(ushort u) { return __uint_as_float(((uint)u) << 16); }

// ---- fp32 -> bf16 convert (layer-0 input) ----
__global__ __launch_bounds__(256) void convert_bf_kernel(
    const float* __restrict__ x, ushort* __restrict__ xbf)
{
    int i = blockIdx.x * 256 + threadIdx.x;
    if (i >= NN * FEAT / 4) return;
    float4 v = ((const float4*)x)[i];
    ushort4 u;
    u.x = f2bf(v.x); u.y = f2bf(v.y); u.z = f2bf(v.z); u.w = f2bf(v.w);
    ((ushort4*)xbf)[i] = u;
}

// ---- MFMA GEMM: h(bf16) = in(bf16) @ W, + per-node logits al_src/al_dst ----
// A = W^T (16x32 frags, staged in LDS fragment-order then cached in VGPRs),
// B = 16 input rows. D[m=out-col][n=node]: col=lane&15 (node), row=quad*4+reg.
__global__ __launch_bounds__(256, 2) void gemm_mfma_kernel(
    const ushort* __restrict__ inbf, const float* __restrict__ W,
    const float* __restrict__ a_src, const float* __restrict__ a_dst,
    ushort* __restrict__ hbf, float* __restrict__ al_s, float* __restrict__ al_d)
{
    __shared__ __align__(16) ushort WA[FEAT * FEAT];   // 32 KiB, fragment-ordered
    const int t = threadIdx.x;
    // stage W (fp32, [k][m]) -> bf16 fragment order: A[m][k] = W[k][m]
    for (int idx = t; idx < FEAT * FEAT; idx += 256) {
        int k = idx >> 7, m = idx & 127;
        int mt = m >> 4, kt = k >> 5, qq = (k >> 3) & 3, j = k & 7;
        int ln = qq * 16 + (m & 15);
        WA[((mt * 4 + kt) * 64 + ln) * 8 + j] = f2bf(W[idx]);
    }
    __syncthreads();

    const int wv = t >> 6, lane = t & 63;
    const int node_l = lane & 15, q = lane >> 4;

    short8 afr[8][4];
    #pragma unroll
    for (int mt = 0; mt < 8; ++mt)
        #pragma unroll
        for (int kt = 0; kt < 4; ++kt)
            afr[mt][kt] = *(const short8*)&WA[((mt * 4 + kt) * 64 + lane) * 8];

    for (int tile = blockIdx.x * 4 + wv; tile < GTILES; tile += gridDim.x * 4) {
        const int n0 = tile * 16;
        const ushort* rowp = inbf + (size_t)(n0 + node_l) * FEAT + q * 8;
        short8 b0 = *(const short8*)(rowp);
        short8 b1 = *(const short8*)(rowp + 32);
        short8 b2 = *(const short8*)(rowp + 64);
        short8 b3 = *(const short8*)(rowp + 96);
        fx4 zero = {0.f, 0.f, 0.f, 0.f};
        fx4 acc[8];
        #pragma unroll
        for (int mt = 0; mt < 8; ++mt) acc[mt] = zero;
        #pragma unroll
        for (int kt = 0; kt < 4; ++kt) {
            short8 b = (kt == 0) ? b0 : (kt == 1) ? b1 : (kt == 2) ? b2 : b3;
            #pragma unroll
            for (int mt = 0; mt < 8; ++mt)
                acc[mt] = __builtin_amdgcn_mfma_f32_16x16x32_bf16(afr[mt][kt], b, acc[mt], 0, 0, 0);
        }
        // epilogue: h store (bf16) + logit partials
        float ps[4] = {0.f, 0.f, 0.f, 0.f};
        float pd[4] = {0.f, 0.f, 0.f, 0.f};
        #pragma unroll
        for (int mt = 0; mt < 8; ++mt) {
            float4 as4 = *(const float4*)(a_src + mt * 16 + q * 4);
            float4 ad4 = *(const float4*)(a_dst + mt * 16 + q * 4);
            ps[mt >> 1] += acc[mt][0] * as4.x + acc[mt][1] * as4.y + acc[mt][2] * as4.z + acc[mt][3] * as4.w;
            pd[mt >> 1] += acc[mt][0] * ad4.x + acc[mt][1] * ad4.y + acc[mt][2] * ad4.z + acc[mt][3] * ad4.w;
            ushort4 hv;
            hv.x = f2bf(acc[mt][0]); hv.y = f2bf(acc[mt][1]);
            hv.z = f2bf(acc[mt][2]); hv.w = f2bf(acc[mt][3]);
            *(ushort4*)(hbf + (size_t)(n0 + node_l) * FEAT + mt * 16 + q * 4) = hv;
        }
        #pragma unroll
        for (int h = 0; h < 4; ++h) {
            ps[h] += __shfl_xor(ps[h], 16); ps[h] += __shfl_xor(ps[h], 32);
            pd[h] += __shfl_xor(pd[h], 16); pd[h] += __shfl_xor(pd[h], 32);
        }
        float vs = (q == 0) ? ps[0] : (q == 1) ? ps[1] : (q == 2) ? ps[2] : ps[3];
        float vd = (q == 0) ? pd[0] : (q == 1) ? pd[1] : (q == 2) ? pd[2] : pd[3];
        al_s[(n0 + node_l) * 4 + q] = vs;
        al_d[(n0 + node_l) * 4 + q] = vd;
    }
}

// ======================= CSR build: bucketed counting sort =======================

__global__ void zero_small_kernel(int* bsize)
{
    int t = threadIdx.x;
    if (t < NBUCK) bsize[t] = 0;
}

__global__ __launch_bounds__(256) void bucket_hist_kernel(
    const int* __restrict__ ei, int E, int* bsize)
{
    __shared__ int lh[NBUCK];
    int t = threadIdx.x;
    if (t < NBUCK) lh[t] = 0;
    __syncthreads();
    int stride = gridDim.x * 256;
    for (int i = blockIdx.x * 256 + t; i < E + NN; i += stride) {
        int d = (i < E) ? ei[E + i] : (i - E);
        atomicAdd(&lh[d >> BSH], 1);
    }
    __syncthreads();
    if (t < NBUCK && lh[t]) atomicAdd(&bsize[t], lh[t]);
}

__global__ void bucket_scan_kernel(const int* __restrict__ bsize, int* bbase, int* bcursor)
{
    if (threadIdx.x == 0) {
        int acc = 0;
        for (int b = 0; b < NBUCK; ++b) { bbase[b] = acc; bcursor[b] = acc; acc += bsize[b]; }
        bbase[NBUCK] = acc;
    }
}

__global__ __launch_bounds__(256) void phaseA_bin_kernel(
    const int* __restrict__ ei, int E, int* bcursor, int2* __restrict__ pairs)
{
    __shared__ int lh[NBUCK], lb[NBUCK];
    int t = threadIdx.x;
    if (t < NBUCK) lh[t] = 0;
    __syncthreads();
    int base = blockIdx.x * (256 * PA_EPT) + t;
    int s[PA_EPT], d[PA_EPT];
    #pragma unroll
    for (int k = 0; k < PA_EPT; ++k) {
        int i = base + k * 256;
        if (i < E)            { s[k] = ei[i]; d[k] = ei[E + i]; }
        else if (i < E + NN)  { s[k] = i - E; d[k] = s[k]; }
        else                  { s[k] = 0; d[k] = -1; }
        if (d[k] >= 0) atomicAdd(&lh[d[k] >> BSH], 1);
    }
    __syncthreads();
    if (t < NBUCK) {
        int c = lh[t];
        lb[t] = c ? atomicAdd(&bcursor[t], c) : 0;
        lh[t] = 0;
    }
    __syncthreads();
    #pragma unroll
    for (int k = 0; k < PA_EPT; ++k) {
        if (d[k] >= 0) {
            int b = d[k] >> BSH;
            int off = atomicAdd(&lh[b], 1);
            pairs[lb[b] + off] = make_int2(d[k], s[k]);
        }
    }
}

__global__ __launch_bounds__(256) void phaseB_kernel(
    const int2* __restrict__ pairs, const int* __restrict__ bbase,
    int* __restrict__ row_ptr, int* __restrict__ colidx, int EP)
{
    __shared__ int nh[BNODES];
    __shared__ int ex[BNODES];
    __shared__ int ss[256];
    __shared__ int img[BCAP];
    int b = blockIdx.x, t = threadIdx.x;
    int node0 = b << BSH;
    int nend = min(NN - node0, BNODES);
    int pb = bbase[b], pe = bbase[b + 1];
    int span = pe - pb;
    for (int j = t; j < BNODES; j += 256) nh[j] = 0;
    __syncthreads();
    for (int i = t; i < span; i += 256)
        atomicAdd(&nh[pairs[pb + i].x - node0], 1);
    __syncthreads();
    int v0 = nh[2 * t], v1 = nh[2 * t + 1];
    int psc = v0 + v1;
    ss[t] = psc;
    __syncthreads();
    #pragma unroll
    for (int off = 1; off < 256; off <<= 1) {
        int x = (t >= off) ? ss[t - off] : 0;
        __syncthreads();
        ss[t] += x;
        __syncthreads();
    }
    int ep = ss[t] - psc;
    ex[2 * t] = ep;
    ex[2 * t + 1] = ep + v0;
    __syncthreads();
    for (int j = t; j < nend; j += 256) row_ptr[node0 + j] = pb + ex[j];
    if (b == NBUCK - 1 && t == 0) row_ptr[NN] = EP;
    for (int j = t; j < BNODES; j += 256) nh[j] = ex[j];   // reuse as cursors
    __syncthreads();
    if (span <= BCAP) {
        for (int i = t; i < span; i += 256) {
            int2 p = pairs[pb + i];
            int pos = atomicAdd(&nh[p.x - node0], 1);
            img[pos] = p.y;
        }
        __syncthreads();
        for (int i = t; i < span; i += 256) colidx[pb + i] = img[i];
    } else {
        for (int i = t; i < span; i += 256) {
            int2 p = pairs[pb + i];
            int pos = atomicAdd(&nh[p.x - node0], 1);
            colidx[pb + pos] = p.y;
        }
    }
}

// ======================= fused softmax + aggregation (bf16 out) =======================
__global__ __launch_bounds__(256) void aggr_csr_kernel(
    const int* __restrict__ row_ptr, const int* __restrict__ colidx,
    const ushort* __restrict__ hbf, const float* __restrict__ al_s,
    const float* __restrict__ al_d, const float* __restrict__ bias,
    ushort* __restrict__ outbf)
{
    int t = threadIdx.x;
    int node = blockIdx.x * 16 + (t >> 4);
    if (node >= NN) return;
    int lane = t & 15;
    int head = lane >> 2;
    float ald_h = al_d[node * 4 + head];
    int beg = row_ptr[node], end = row_ptr[node + 1];

    float ssum = 0.f;
    float a0=0.f,a1=0.f,a2=0.f,a3=0.f,a4=0.f,a5=0.f,a6=0.f,a7=0.f;

    int p = beg;
    for (; p + 4 <= end; p += 4) {
        int s0 = colidx[p], s1 = colidx[p+1], s2 = colidx[p+2], s3 = colidx[p+3];
        float w0 = __expf(lrelu(al_s[s0*4 + head] + ald_h));
        float w1 = __expf(lrelu(al_s[s1*4 + head] + ald_h));
        float w2 = __expf(lrelu(al_s[s2*4 + head] + ald_h));
        float w3 = __expf(lrelu(al_s[s3*4 + head] + ald_h));
        uint4 h0 = ((const uint4*)(hbf + (size_t)s0 * FEAT))[lane];
        uint4 h1 = ((const uint4*)(hbf + (size_t)s1 * FEAT))[lane];
        uint4 h2 = ((const uint4*)(hbf + (size_t)s2 * FEAT))[lane];
        uint4 h3 = ((const uint4*)(hbf + (size_t)s3 * FEAT))[lane];
        ssum += (w0 + w1) + (w2 + w3);
        a0 = fmaf(w0, bf_lo(h0.x), a0); a1 = fmaf(w0, bf_hi(h0.x), a1);
        a2 = fmaf(w0, bf_lo(h0.y), a2); a3 = fmaf(w0, bf_hi(h0.y), a3);
        a4 = fmaf(w0, bf_lo(h0.z), a4); a5 = fmaf(w0, bf_hi(h0.z), a5);
        a6 = fmaf(w0, bf_lo(h0.w), a6); a7 = fmaf(w0, bf_hi(h0.w), a7);
        a0 = fmaf(w1, bf_lo(h1.x), a0); a1 = fmaf(w1, bf_hi(h1.x), a1);
        a2 = fmaf(w1, bf_lo(h1.y), a2); a3 = fmaf(w1, bf_hi(h1.y), a3);
        a4 = fmaf(w1, bf_lo(h1.z), a4); a5 = fmaf(w1, bf_hi(h1.z), a5);
        a6 = fmaf(w1, bf_lo(h1.w), a6); a7 = fmaf(w1, bf_hi(h1.w), a7);
        a0 = fmaf(w2, bf_lo(h2.x), a0); a1 = fmaf(w2, bf_hi(h2.x), a1);
        a2 = fmaf(w2, bf_lo(h2.y), a2); a3 = fmaf(w2, bf_hi(h2.y), a3);
        a4 = fmaf(w2, bf_lo(h2.z), a4); a5 = fmaf(w2, bf_hi(h2.z), a5);
        a6 = fmaf(w2, bf_lo(h2.w), a6); a7 = fmaf(w2, bf_hi(h2.w), a7);
        a0 = fmaf(w3, bf_lo(h3.x), a0); a1 = fmaf(w3, bf_hi(h3.x), a1);
        a2 = fmaf(w3, bf_lo(h3.y), a2); a3 = fmaf(w3, bf_hi(h3.y), a3);
        a4 = fmaf(w3, bf_lo(h3.z), a4); a5 = fmaf(w3, bf_hi(h3.z), a5);
        a6 = fmaf(w3, bf_lo(h3.w), a6); a7 = fmaf(w3, bf_hi(h3.w), a7);
    }
    for (; p < end; ++p) {
        int sn = colidx[p];
        float w = __expf(lrelu(al_s[sn*4 + head] + ald_h));
        uint4 hv = ((const uint4*)(hbf + (size_t)sn * FEAT))[lane];
        ssum += w;
        a0 = fmaf(w, bf_lo(hv.x), a0); a1 = fmaf(w, bf_hi(hv.x), a1);
        a2 = fmaf(w, bf_lo(hv.y), a2); a3 = fmaf(w, bf_hi(hv.y), a3);
        a4 = fmaf(w, bf_lo(hv.z), a4); a5 = fmaf(w, bf_hi(hv.z), a5);
        a6 = fmaf(w, bf_lo(hv.w), a6); a7 = fmaf(w, bf_hi(hv.w), a7);
    }
    float inv = 1.f / (ssum + 1e-16f);
    const float* bp = bias + lane * 8;
    float o[8] = {a0,a1,a2,a3,a4,a5,a6,a7};
    #pragma unroll
    for (int k = 0; k < 8; ++k) {
        float v = o[k] * inv + bp[k];
        o[k] = v > 0.f ? v : __expf(v) - 1.f;
    }
    uint p01 = (uint)f2bf(o[0]) | ((uint)f2bf(o[1]) << 16);
    uint p23 = (uint)f2bf(o[2]) | ((uint)f2bf(o[3]) << 16);
    uint p45 = (uint)f2bf(o[4]) | ((uint)f2bf(o[5]) << 16);
    uint p67 = (uint)f2bf(o[6]) | ((uint)f2bf(o[7]) << 16);
    uint4 u; u.x = p01; u.y = p23; u.z = p45; u.w = p67;
    ((uint4*)(outbf + (size_t)node * FEAT))[lane] = u;
}

// ---- final FC (128 -> 10, bf16 in) + log_softmax; one wave per node ----
__global__ __launch_bounds__(256) void fc_kernel(
    const ushort* __restrict__ hbf, const float* __restrict__ fcW,
    const float* __restrict__ fcb, float* __restrict__ out)
{
    __shared__ float Wl[FEAT * 10];
    __shared__ float bl[10];
    int t = threadIdx.x;
    for (int i = t; i < FEAT * 10; i += 256) Wl[i] = fcW[i];
    if (t < 10) bl[t] = fcb[t];
    __syncthreads();
    int wv = t >> 6, lane = t & 63;
    int n = blockIdx.x * 4 + wv;
    if (n >= NN) return;
    float x0 = bfu(hbf[(size_t)n * FEAT + lane]);
    float x1 = bfu(hbf[(size_t)n * FEAT + 64 + lane]);
    float lg[10];
    #pragma unroll
    for (int k = 0; k < 10; ++k)
        lg[k] = x0 * Wl[lane * 10 + k] + x1 * Wl[(64 + lane) * 10 + k];
    #pragma unroll
    for (int off = 32; off >= 1; off >>= 1) {
        #pragma unroll
        for (int k = 0; k < 10; ++k) lg[k] += __shfl_xor(lg[k], off);
    }
    if (lane == 0) {
        float mx = -1e30f;
        #pragma unroll
        for (int k = 0; k < 10; ++k) { lg[k] += bl[k]; mx = fmaxf(mx, lg[k]); }
        float se = 0.f;
        #pragma unroll
        for (int k = 0; k < 10; ++k) se += __expf(lg[k] - mx);
        float lse = mx + __logf(se);
        #pragma unroll
        for (int k = 0; k < 10; ++k) out[(size_t)n * 10 + k] = lg[k] - lse;
    }
}

extern "C" void kernel_launch(void* const* d_in, const int* in_sizes, int n_in,
                              void* d_out, int out_size, void* d_ws, size_t ws_size,
                              hipStream_t stream)
{
    const float* x   = (const float*)d_in[0];
    const int*   ei  = (const int*)d_in[1];
    const float* W[3]   = {(const float*)d_in[2], (const float*)d_in[6],  (const float*)d_in[10]};
    const float* asr[3] = {(const float*)d_in[3], (const float*)d_in[7],  (const float*)d_in[11]};
    const float* ads[3] = {(const float*)d_in[4], (const float*)d_in[8],  (const float*)d_in[12]};
    const float* bs[3]  = {(const float*)d_in[5], (const float*)d_in[9],  (const float*)d_in[13]};
    const float* fcW = (const float*)d_in[14];
    const float* fcb = (const float*)d_in[15];
    const int E  = in_sizes[1] / 2;
    const int EP = E + NN;

    // workspace layout
    ushort* xbf  = (ushort*)d_ws;                      // [NN*FEAT] bf16 (layer-0 in)
    ushort* hbf  = xbf + (size_t)NN * FEAT;            // [NN*FEAT] bf16 (gemm out)
    ushort* ybf  = hbf + (size_t)NN * FEAT;            // [NN*FEAT] bf16 (aggr out)
    float* als   = (float*)(ybf + (size_t)NN * FEAT);  // [NN*4]
    float* ald   = als + (size_t)NN * NHEAD;           // [NN*4]
    int* row_ptr = (int*)(ald + (size_t)NN * NHEAD);   // [NN+1]
    int* bsize   = row_ptr + NN + 1;                   // [NBUCK]
    int* bbase   = bsize + NBUCK;                      // [NBUCK+1]
    int* bcursor = bbase + NBUCK + 1;                  // [NBUCK]
    int2* pairs  = (int2*)(bcursor + NBUCK);           // [EP]
    int* colidx  = (int*)(pairs + (size_t)EP);         // [EP]

    // ---- CSR build (once; graph is layer-invariant) ----
    zero_small_kernel<<<1, 256, 0, stream>>>(bsize);
    bucket_hist_kernel<<<1024, 256, 0, stream>>>(ei, E, bsize);
    bucket_scan_kernel<<<1, 64, 0, stream>>>(bsize, bbase, bcursor);
    phaseA_bin_kernel<<<(EP + 256*PA_EPT - 1) / (256*PA_EPT), 256, 0, stream>>>(ei, E, bcursor, pairs);
    phaseB_kernel<<<NBUCK, 256, 0, stream>>>(pairs, bbase, row_ptr, colidx, EP);

    convert_bf_kernel<<<(NN * FEAT / 4 + 255) / 256, 256, 0, stream>>>(x, xbf);

    const ushort* fin = xbf;
    for (int l = 0; l < 3; ++l) {
        gemm_mfma_kernel<<<512, 256, 0, stream>>>(fin, W[l], asr[l], ads[l], hbf, als, ald);
        aggr_csr_kernel<<<(NN + 15) / 16, 256, 0, stream>>>(row_ptr, colidx, hbf, als, ald, bs[l], ybf);
        fin = ybf;
    }
    fc_kernel<<<(NN + 3) / 4, 256, 0, stream>>>(ybf, fcW, fcb, (float*)d_out);
}

// Round 7
// 509.594 us; speedup vs baseline: 21.2975x; 1.1044x over previous
//
#include <hip/hip_runtime.h>
#include <math.h>

#define NN 100000
#define FEAT 128
#define NHEAD 4
#define BSH 9                      // 512 nodes per bucket
#define BNODES 512
#define NBUCK 196                  // ceil(NN / 512)
#define BCAP 16384                 // colidx LDS image capacity (avg span ~8700)
#define PA_EPT 16                  // phase-A edges per thread
#define GTILES 6250                // 100000 / 16

typedef unsigned int uint;
typedef unsigned short ushort;
typedef __attribute__((ext_vector_type(8))) short short8;
typedef __attribute__((ext_vector_type(4))) float fx4;

__device__ __forceinline__ float lrelu(float v) { return v > 0.f ? v : 0.2f * v; }

__device__ __forceinline__ ushort f2bf(float f) {          // RNE bf16
    uint u = __float_as_uint(f);
    return (ushort)((u + 0x7fffu + ((u >> 16) & 1u)) >> 16);
}
__device__ __forceinline__ float bf_lo(uint u) { return __uint_as_float(u << 16); }
__device__ __forceinline__ float bf_hi(uint u) { return __uint_as_float(u & 0xffff0000u); }

// ---- fp32 -> bf16 convert (layer-0 input) ----
__global__ __launch_bounds__(256) void convert_bf_kernel(
    const float* __restrict__ x, ushort* __restrict__ xbf)
{
    int i = blockIdx.x * 256 + threadIdx.x;
    if (i >= NN * FEAT / 4) return;
    float4 v = ((const float4*)x)[i];
    ushort4 u;
    u.x = f2bf(v.x); u.y = f2bf(v.y); u.z = f2bf(v.z); u.w = f2bf(v.w);
    ((ushort4*)xbf)[i] = u;
}

// ---- MFMA GEMM: h(bf16) = in(bf16) @ W, + per-node logits al_src/al_dst ----
__global__ __launch_bounds__(256, 2) void gemm_mfma_kernel(
    const ushort* __restrict__ inbf, const float* __restrict__ W,
    const float* __restrict__ a_src, const float* __restrict__ a_dst,
    ushort* __restrict__ hbf, float* __restrict__ al_s, float* __restrict__ al_d)
{
    __shared__ __align__(16) ushort WA[FEAT * FEAT];   // 32 KiB, fragment-ordered
    const int t = threadIdx.x;
    for (int idx = t; idx < FEAT * FEAT; idx += 256) {
        int k = idx >> 7, m = idx & 127;
        int mt = m >> 4, kt = k >> 5, qq = (k >> 3) & 3, j = k & 7;
        int ln = qq * 16 + (m & 15);
        WA[((mt * 4 + kt) * 64 + ln) * 8 + j] = f2bf(W[idx]);
    }
    __syncthreads();

    const int wv = t >> 6, lane = t & 63;
    const int node_l = lane & 15, q = lane >> 4;

    short8 afr[8][4];
    #pragma unroll
    for (int mt = 0; mt < 8; ++mt)
        #pragma unroll
        for (int kt = 0; kt < 4; ++kt)
            afr[mt][kt] = *(const short8*)&WA[((mt * 4 + kt) * 64 + lane) * 8];

    for (int tile = blockIdx.x * 4 + wv; tile < GTILES; tile += gridDim.x * 4) {
        const int n0 = tile * 16;
        const ushort* rowp = inbf + (size_t)(n0 + node_l) * FEAT + q * 8;
        short8 b0 = *(const short8*)(rowp);
        short8 b1 = *(const short8*)(rowp + 32);
        short8 b2 = *(const short8*)(rowp + 64);
        short8 b3 = *(const short8*)(rowp + 96);
        fx4 zero = {0.f, 0.f, 0.f, 0.f};
        fx4 acc[8];
        #pragma unroll
        for (int mt = 0; mt < 8; ++mt) acc[mt] = zero;
        #pragma unroll
        for (int kt = 0; kt < 4; ++kt) {
            short8 b = (kt == 0) ? b0 : (kt == 1) ? b1 : (kt == 2) ? b2 : b3;
            #pragma unroll
            for (int mt = 0; mt < 8; ++mt)
                acc[mt] = __builtin_amdgcn_mfma_f32_16x16x32_bf16(afr[mt][kt], b, acc[mt], 0, 0, 0);
        }
        float ps[4] = {0.f, 0.f, 0.f, 0.f};
        float pd[4] = {0.f, 0.f, 0.f, 0.f};
        #pragma unroll
        for (int mt = 0; mt < 8; ++mt) {
            float4 as4 = *(const float4*)(a_src + mt * 16 + q * 4);
            float4 ad4 = *(const float4*)(a_dst + mt * 16 + q * 4);
            ps[mt >> 1] += acc[mt][0] * as4.x + acc[mt][1] * as4.y + acc[mt][2] * as4.z + acc[mt][3] * as4.w;
            pd[mt >> 1] += acc[mt][0] * ad4.x + acc[mt][1] * ad4.y + acc[mt][2] * ad4.z + acc[mt][3] * ad4.w;
            ushort4 hv;
            hv.x = f2bf(acc[mt][0]); hv.y = f2bf(acc[mt][1]);
            hv.z = f2bf(acc[mt][2]); hv.w = f2bf(acc[mt][3]);
            *(ushort4*)(hbf + (size_t)(n0 + node_l) * FEAT + mt * 16 + q * 4) = hv;
        }
        #pragma unroll
        for (int h = 0; h < 4; ++h) {
            ps[h] += __shfl_xor(ps[h], 16); ps[h] += __shfl_xor(ps[h], 32);
            pd[h] += __shfl_xor(pd[h], 16); pd[h] += __shfl_xor(pd[h], 32);
        }
        float vs = (q == 0) ? ps[0] : (q == 1) ? ps[1] : (q == 2) ? ps[2] : ps[3];
        float vd = (q == 0) ? pd[0] : (q == 1) ? pd[1] : (q == 2) ? pd[2] : pd[3];
        al_s[(n0 + node_l) * 4 + q] = vs;
        al_d[(n0 + node_l) * 4 + q] = vd;
    }
}

// ======================= CSR build: bucketed counting sort =======================

__global__ void zero_small_kernel(int* bsize)
{
    int t = threadIdx.x;
    if (t < NBUCK) bsize[t] = 0;
}

__global__ __launch_bounds__(256) void bucket_hist_kernel(
    const int* __restrict__ ei, int E, int* bsize)
{
    __shared__ int lh[NBUCK];
    int t = threadIdx.x;
    if (t < NBUCK) lh[t] = 0;
    __syncthreads();
    int stride = gridDim.x * 256;
    for (int i = blockIdx.x * 256 + t; i < E + NN; i += stride) {
        int d = (i < E) ? ei[E + i] : (i - E);
        atomicAdd(&lh[d >> BSH], 1);
    }
    __syncthreads();
    if (t < NBUCK && lh[t]) atomicAdd(&bsize[t], lh[t]);
}

__global__ void bucket_scan_kernel(const int* __restrict__ bsize, int* bbase, int* bcursor)
{
    if (threadIdx.x == 0) {
        int acc = 0;
        for (int b = 0; b < NBUCK; ++b) { bbase[b] = acc; bcursor[b] = acc; acc += bsize[b]; }
        bbase[NBUCK] = acc;
    }
}

__global__ __launch_bounds__(256) void phaseA_bin_kernel(
    const int* __restrict__ ei, int E, int* bcursor, int2* __restrict__ pairs)
{
    __shared__ int lh[NBUCK], lb[NBUCK];
    int t = threadIdx.x;
    if (t < NBUCK) lh[t] = 0;
    __syncthreads();
    int base = blockIdx.x * (256 * PA_EPT) + t;
    int s[PA_EPT], d[PA_EPT];
    #pragma unroll
    for (int k = 0; k < PA_EPT; ++k) {
        int i = base + k * 256;
        if (i < E)            { s[k] = ei[i]; d[k] = ei[E + i]; }
        else if (i < E + NN)  { s[k] = i - E; d[k] = s[k]; }
        else                  { s[k] = 0; d[k] = -1; }
        if (d[k] >= 0) atomicAdd(&lh[d[k] >> BSH], 1);
    }
    __syncthreads();
    if (t < NBUCK) {
        int c = lh[t];
        lb[t] = c ? atomicAdd(&bcursor[t], c) : 0;
        lh[t] = 0;
    }
    __syncthreads();
    #pragma unroll
    for (int k = 0; k < PA_EPT; ++k) {
        if (d[k] >= 0) {
            int b = d[k] >> BSH;
            int off = atomicAdd(&lh[b], 1);
            pairs[lb[b] + off] = make_int2(d[k], s[k]);
        }
    }
}

__global__ __launch_bounds__(256) void phaseB_kernel(
    const int2* __restrict__ pairs, const int* __restrict__ bbase,
    int* __restrict__ row_ptr, int* __restrict__ colidx, int EP)
{
    __shared__ int nh[BNODES];
    __shared__ int ex[BNODES];
    __shared__ int ss[256];
    __shared__ int img[BCAP];
    int b = blockIdx.x, t = threadIdx.x;
    int node0 = b << BSH;
    int nend = min(NN - node0, BNODES);
    int pb = bbase[b], pe = bbase[b + 1];
    int span = pe - pb;
    for (int j = t; j < BNODES; j += 256) nh[j] = 0;
    __syncthreads();
    for (int i = t; i < span; i += 256)
        atomicAdd(&nh[pairs[pb + i].x - node0], 1);
    __syncthreads();
    int v0 = nh[2 * t], v1 = nh[2 * t + 1];
    int psc = v0 + v1;
    ss[t] = psc;
    __syncthreads();
    #pragma unroll
    for (int off = 1; off < 256; off <<= 1) {
        int x = (t >= off) ? ss[t - off] : 0;
        __syncthreads();
        ss[t] += x;
        __syncthreads();
    }
    int ep = ss[t] - psc;
    ex[2 * t] = ep;
    ex[2 * t + 1] = ep + v0;
    __syncthreads();
    for (int j = t; j < nend; j += 256) row_ptr[node0 + j] = pb + ex[j];
    if (b == NBUCK - 1 && t == 0) row_ptr[NN] = EP;
    for (int j = t; j < BNODES; j += 256) nh[j] = ex[j];   // reuse as cursors
    __syncthreads();
    if (span <= BCAP) {
        for (int i = t; i < span; i += 256) {
            int2 p = pairs[pb + i];
            int pos = atomicAdd(&nh[p.x - node0], 1);
            img[pos] = p.y;
        }
        __syncthreads();
        for (int i = t; i < span; i += 256) colidx[pb + i] = img[i];
    } else {
        for (int i = t; i < span; i += 256) {
            int2 p = pairs[pb + i];
            int pos = atomicAdd(&nh[p.x - node0], 1);
            colidx[pb + pos] = p.y;
        }
    }
}

// ======================= fused softmax + aggregation (bf16 out) =======================
#define AGGR_STEP(hv, wgt)                                                    \
    a0 = fmaf(wgt, bf_lo(hv.x), a0); a1 = fmaf(wgt, bf_hi(hv.x), a1);        \
    a2 = fmaf(wgt, bf_lo(hv.y), a2); a3 = fmaf(wgt, bf_hi(hv.y), a3);        \
    a4 = fmaf(wgt, bf_lo(hv.z), a4); a5 = fmaf(wgt, bf_hi(hv.z), a5);        \
    a6 = fmaf(wgt, bf_lo(hv.w), a6); a7 = fmaf(wgt, bf_hi(hv.w), a7);

__global__ __launch_bounds__(256) void aggr_csr_kernel(
    const int* __restrict__ row_ptr, const int* __restrict__ colidx,
    const ushort* __restrict__ hbf, const float* __restrict__ al_s,
    const float* __restrict__ al_d, const float* __restrict__ bias,
    ushort* __restrict__ outbf)
{
    int t = threadIdx.x;
    int node = blockIdx.x * 16 + (t >> 4);
    if (node >= NN) return;
    int lane = t & 15;
    int head = lane >> 2;
    float ald_h = al_d[node * 4 + head];
    int beg = row_ptr[node], end = row_ptr[node + 1];

    float ssum = 0.f;
    float a0=0.f,a1=0.f,a2=0.f,a3=0.f,a4=0.f,a5=0.f,a6=0.f,a7=0.f;

    int p = beg;
    for (; p + 8 <= end; p += 8) {
        int s0 = colidx[p],   s1 = colidx[p+1], s2 = colidx[p+2], s3 = colidx[p+3];
        int s4 = colidx[p+4], s5 = colidx[p+5], s6 = colidx[p+6], s7 = colidx[p+7];
        float w0 = __expf(lrelu(al_s[s0*4 + head] + ald_h));
        float w1 = __expf(lrelu(al_s[s1*4 + head] + ald_h));
        float w2 = __expf(lrelu(al_s[s2*4 + head] + ald_h));
        float w3 = __expf(lrelu(al_s[s3*4 + head] + ald_h));
        float w4 = __expf(lrelu(al_s[s4*4 + head] + ald_h));
        float w5 = __expf(lrelu(al_s[s5*4 + head] + ald_h));
        float w6 = __expf(lrelu(al_s[s6*4 + head] + ald_h));
        float w7 = __expf(lrelu(al_s[s7*4 + head] + ald_h));
        uint4 h0 = ((const uint4*)(hbf + (size_t)s0 * FEAT))[lane];
        uint4 h1 = ((const uint4*)(hbf + (size_t)s1 * FEAT))[lane];
        uint4 h2 = ((const uint4*)(hbf + (size_t)s2 * FEAT))[lane];
        uint4 h3 = ((const uint4*)(hbf + (size_t)s3 * FEAT))[lane];
        uint4 h4 = ((const uint4*)(hbf + (size_t)s4 * FEAT))[lane];
        uint4 h5 = ((const uint4*)(hbf + (size_t)s5 * FEAT))[lane];
        uint4 h6 = ((const uint4*)(hbf + (size_t)s6 * FEAT))[lane];
        uint4 h7 = ((const uint4*)(hbf + (size_t)s7 * FEAT))[lane];
        ssum += ((w0 + w1) + (w2 + w3)) + ((w4 + w5) + (w6 + w7));
        AGGR_STEP(h0, w0) AGGR_STEP(h1, w1) AGGR_STEP(h2, w2) AGGR_STEP(h3, w3)
        AGGR_STEP(h4, w4) AGGR_STEP(h5, w5) AGGR_STEP(h6, w6) AGGR_STEP(h7, w7)
    }
    for (; p + 4 <= end; p += 4) {
        int s0 = colidx[p], s1 = colidx[p+1], s2 = colidx[p+2], s3 = colidx[p+3];
        float w0 = __expf(lrelu(al_s[s0*4 + head] + ald_h));
        float w1 = __expf(lrelu(al_s[s1*4 + head] + ald_h));
        float w2 = __expf(lrelu(al_s[s2*4 + head] + ald_h));
        float w3 = __expf(lrelu(al_s[s3*4 + head] + ald_h));
        uint4 h0 = ((const uint4*)(hbf + (size_t)s0 * FEAT))[lane];
        uint4 h1 = ((const uint4*)(hbf + (size_t)s1 * FEAT))[lane];
        uint4 h2 = ((const uint4*)(hbf + (size_t)s2 * FEAT))[lane];
        uint4 h3 = ((const uint4*)(hbf + (size_t)s3 * FEAT))[lane];
        ssum += (w0 + w1) + (w2 + w3);
        AGGR_STEP(h0, w0) AGGR_STEP(h1, w1) AGGR_STEP(h2, w2) AGGR_STEP(h3, w3)
    }
    for (; p < end; ++p) {
        int sn = colidx[p];
        float wq = __expf(lrelu(al_s[sn*4 + head] + ald_h));
        uint4 hv = ((const uint4*)(hbf + (size_t)sn * FEAT))[lane];
        ssum += wq;
        AGGR_STEP(hv, wq)
    }
    float inv = 1.f / (ssum + 1e-16f);
    const float* bp = bias + lane * 8;
    float o[8] = {a0,a1,a2,a3,a4,a5,a6,a7};
    #pragma unroll
    for (int k = 0; k < 8; ++k) {
        float v = o[k] * inv + bp[k];
        o[k] = v > 0.f ? v : __expf(v) - 1.f;
    }
    uint4 u;
    u.x = (uint)f2bf(o[0]) | ((uint)f2bf(o[1]) << 16);
    u.y = (uint)f2bf(o[2]) | ((uint)f2bf(o[3]) << 16);
    u.z = (uint)f2bf(o[4]) | ((uint)f2bf(o[5]) << 16);
    u.w = (uint)f2bf(o[6]) | ((uint)f2bf(o[7]) << 16);
    ((uint4*)(outbf + (size_t)node * FEAT))[lane] = u;
}

// ---- final FC (128 -> 10, bf16 in) + log_softmax; THREAD per node ----
__global__ __launch_bounds__(256) void fc_kernel(
    const ushort* __restrict__ hbf, const float* __restrict__ fcW,
    const float* __restrict__ fcb, float* __restrict__ out)
{
    __shared__ float WT[10][FEAT];   // 5 KiB
    __shared__ float bl[10];
    int t = threadIdx.x;
    for (int i = t; i < FEAT * 10; i += 256) {
        int k = i / 10, c = i % 10;
        WT[c][k] = fcW[i];
    }
    if (t < 10) bl[t] = fcb[t];
    __syncthreads();
    int n = blockIdx.x * 256 + t;
    if (n >= NN) return;
    const uint4* row = (const uint4*)(hbf + (size_t)n * FEAT);
    float lg[10];
    #pragma unroll
    for (int c = 0; c < 10; ++c) lg[c] = bl[c];
    #pragma unroll 4
    for (int k8 = 0; k8 < 16; ++k8) {
        uint4 u = row[k8];
        float x0 = bf_lo(u.x), x1 = bf_hi(u.x), x2 = bf_lo(u.y), x3 = bf_hi(u.y);
        float x4 = bf_lo(u.z), x5 = bf_hi(u.z), x6 = bf_lo(u.w), x7 = bf_hi(u.w);
        #pragma unroll
        for (int c = 0; c < 10; ++c) {
            const float* wr = &WT[c][k8 * 8];
            float4 wa = *(const float4*)(wr);
            float4 wb = *(const float4*)(wr + 4);
            float acc = fmaf(x0, wa.x, fmaf(x1, wa.y, fmaf(x2, wa.z, x3 * wa.w)));
            acc = fmaf(x4, wb.x, fmaf(x5, wb.y, fmaf(x6, wb.z, fmaf(x7, wb.w, acc))));
            lg[c] += acc;
        }
    }
    float mx = lg[0];
    #pragma unroll
    for (int c = 1; c < 10; ++c) mx = fmaxf(mx, lg[c]);
    float se = 0.f;
    #pragma unroll
    for (int c = 0; c < 10; ++c) se += __expf(lg[c] - mx);
    float lse = mx + __logf(se);
    float2* op = (float2*)(out + (size_t)n * 10);
    #pragma unroll
    for (int c = 0; c < 5; ++c)
        op[c] = make_float2(lg[2*c] - lse, lg[2*c + 1] - lse);
}

extern "C" void kernel_launch(void* const* d_in, const int* in_sizes, int n_in,
                              void* d_out, int out_size, void* d_ws, size_t ws_size,
                              hipStream_t stream)
{
    const float* x   = (const float*)d_in[0];
    const int*   ei  = (const int*)d_in[1];
    const float* W[3]   = {(const float*)d_in[2], (const float*)d_in[6],  (const float*)d_in[10]};
    const float* asr[3] = {(const float*)d_in[3], (const float*)d_in[7],  (const float*)d_in[11]};
    const float* ads[3] = {(const float*)d_in[4], (const float*)d_in[8],  (const float*)d_in[12]};
    const float* bs[3]  = {(const float*)d_in[5], (const float*)d_in[9],  (const float*)d_in[13]};
    const float* fcW = (const float*)d_in[14];
    const float* fcb = (const float*)d_in[15];
    const int E  = in_sizes[1] / 2;
    const int EP = E + NN;

    // workspace layout
    ushort* xbf  = (ushort*)d_ws;                      // [NN*FEAT] bf16 (layer-0 in)
    ushort* hbf  = xbf + (size_t)NN * FEAT;            // [NN*FEAT] bf16 (gemm out)
    ushort* ybf  = hbf + (size_t)NN * FEAT;            // [NN*FEAT] bf16 (aggr out)
    float* als   = (float*)(ybf + (size_t)NN * FEAT);  // [NN*4]
    float* ald   = als + (size_t)NN * NHEAD;           // [NN*4]
    int* row_ptr = (int*)(ald + (size_t)NN * NHEAD);   // [NN+1]
    int* bsize   = row_ptr + NN + 1;                   // [NBUCK]
    int* bbase   = bsize + NBUCK;                      // [NBUCK+1]
    int* bcursor = bbase + NBUCK + 1;                  // [NBUCK]
    int2* pairs  = (int2*)(bcursor + NBUCK);           // [EP]
    int* colidx  = (int*)(pairs + (size_t)EP);         // [EP]

    // ---- CSR build (once; graph is layer-invariant) ----
    zero_small_kernel<<<1, 256, 0, stream>>>(bsize);
    bucket_hist_kernel<<<1024, 256, 0, stream>>>(ei, E, bsize);
    bucket_scan_kernel<<<1, 64, 0, stream>>>(bsize, bbase, bcursor);
    phaseA_bin_kernel<<<(EP + 256*PA_EPT - 1) / (256*PA_EPT), 256, 0, stream>>>(ei, E, bcursor, pairs);
    phaseB_kernel<<<NBUCK, 256, 0, stream>>>(pairs, bbase, row_ptr, colidx, EP);

    convert_bf_kernel<<<(NN * FEAT / 4 + 255) / 256, 256, 0, stream>>>(x, xbf);

    const ushort* fin = xbf;
    for (int l = 0; l < 3; ++l) {
        gemm_mfma_kernel<<<512, 256, 0, stream>>>(fin, W[l], asr[l], ads[l], hbf, als, ald);
        aggr_csr_kernel<<<(NN + 15) / 16, 256, 0, stream>>>(row_ptr, colidx, hbf, als, ald, bs[l], ybf);
        fin = ybf;
    }
    fc_kernel<<<(NN + 255) / 256, 256, 0, stream>>>(ybf, fcW, fcb, (float*)d_out);
}